// Round 2
// baseline (2795.672 us; speedup 1.0000x reference)
//
#include <hip/hip_runtime.h>
#include <stdint.h>

typedef unsigned short u16;
typedef unsigned int u32;

#define N_IMG 4
#define C_CH 512
#define HW_SP 1024
#define NHEAD 8
#define DHEAD 128
#define SEQ 512
#define KCONV 4608                       // C*9
#define TSLOT (N_IMG * NHEAD * SEQ * DHEAD)  // 2097152 elements per tensor

__device__ __forceinline__ float bf2f(u16 u) {
    union { u32 i; float f; } v; v.i = ((u32)u) << 16; return v.f;
}
__device__ __forceinline__ u16 f2bf(float f) {
    union { u32 i; float f; } v; v.f = f;
    u32 u = v.i;
    return (u16)((u + 0x7FFFu + ((u >> 16) & 1u)) >> 16);  // RNE
}

// ---------------------------------------------------------------------------
// Conv 3x3 (pad 1) as implicit GEMM: out[m=n*1024+s][co], M=4096, N=512, K=4608
// fp32 inputs; output written bf16 in head-split layout [n][head][co][dd].
// Tile 64x64, BK=16, 256 threads, 4x4 micro-tile, fp32 accumulate.
// ---------------------------------------------------------------------------
__global__ __launch_bounds__(256) void conv3x3_kernel(
    const float* __restrict__ x,  // [4][512][32][32] fp32
    const float* __restrict__ w,  // [512][512][3][3] fp32
    u16* __restrict__ out)        // [4][8][512][128] bf16
{
    __shared__ float As[16][64];  // As[k][m]
    __shared__ float Bs[16][64];  // Bs[k][co]

    const int t  = threadIdx.x;
    const int mb = blockIdx.x;    // 0..63
    const int nb = blockIdx.y;    // 0..7

    const int a_kk = t >> 4;          // 0..15
    const int a_m0 = (t & 15) * 4;    // 0..60
    const int b_co = t >> 2;          // 0..63
    const int b_kq = t & 3;           // 0..3

    const int tm = (t & 15) * 4;      // m offset of micro-tile
    const int tn = (t >> 4) * 4;      // co offset of micro-tile

    float acc[4][4] = {};

    for (int kb = 0; kb < KCONV; kb += 16) {
        // ---- stage A (im2col gather) ----
        {
            int k  = kb + a_kk;
            int ci = k / 9;
            int r  = k - ci * 9;
            int ky = r / 3;
            int kx = r - ky * 3;
            int mbase = mb * 64 + a_m0;
            #pragma unroll
            for (int j = 0; j < 4; ++j) {
                int m  = mbase + j;
                int n  = m >> 10;
                int s  = m & 1023;
                int y  = (s >> 5) + ky - 1;
                int xx = (s & 31) + kx - 1;
                float v = 0.0f;
                if ((unsigned)y < 32u && (unsigned)xx < 32u)
                    v = x[((n * 512 + ci) * 32 + y) * 32 + xx];
                As[a_kk][a_m0 + j] = v;
            }
        }
        // ---- stage B (weights, transposed into k-major) ----
        {
            const float* wp = w + (size_t)(nb * 64 + b_co) * 4608 + kb + b_kq * 4;
            float4 u = *(const float4*)wp;
            Bs[b_kq * 4 + 0][b_co] = u.x;
            Bs[b_kq * 4 + 1][b_co] = u.y;
            Bs[b_kq * 4 + 2][b_co] = u.z;
            Bs[b_kq * 4 + 3][b_co] = u.w;
        }
        __syncthreads();
        #pragma unroll
        for (int kk = 0; kk < 16; ++kk) {
            float4 av = *(const float4*)&As[kk][tm];
            float4 bv = *(const float4*)&Bs[kk][tn];
            float a0[4] = {av.x, av.y, av.z, av.w};
            float b0[4] = {bv.x, bv.y, bv.z, bv.w};
            #pragma unroll
            for (int i = 0; i < 4; ++i)
                #pragma unroll
                for (int j = 0; j < 4; ++j)
                    acc[i][j] += a0[i] * b0[j];
        }
        __syncthreads();
    }

    // epilogue: permuted write into [n][head][co][dd], bf16
    #pragma unroll
    for (int i = 0; i < 4; ++i) {
        int m    = mb * 64 + tm + i;
        int n    = m >> 10;
        int s    = m & 1023;
        int head = s >> 7;
        int dd   = s & 127;
        u16* op = out + ((size_t)(n * 8 + head) * 512) * 128 + dd;
        #pragma unroll
        for (int j = 0; j < 4; ++j) {
            int co = nb * 64 + tn + j;
            op[(size_t)co * 128] = f2bf(acc[i][j]);
        }
    }
}

// ---------------------------------------------------------------------------
// Flash-style attention, fp32 math, bf16 I/O (workspace tensors).
// One block = (n*head, q-tile of 32 rows). K/V chunks of 32 rows staged in LDS.
// Wave w, half h owns rows w*8+h*4..+3 in both S- and PV-phase, so
// online-softmax state (m, l, alpha) stays in registers.
// ---------------------------------------------------------------------------
__global__ __launch_bounds__(256) void attn_kernel(
    const u16* __restrict__ Q,   // [32][512][128]
    const u16* __restrict__ K,
    const u16* __restrict__ V,
    u16* __restrict__ O)
{
    __shared__ float Qs[32][132];
    __shared__ float Kc[32][132];
    __shared__ float Vc[32][128];
    __shared__ float Ps[32][33];

    const int t     = threadIdx.x;
    const int lane  = t & 63;
    const int wave  = t >> 6;
    const int k32   = lane & 31;
    const int qbase = wave * 8 + (lane >> 5) * 4;  // 4 rows owned by this lane
    const int q0    = blockIdx.x * 32;
    const int nh    = blockIdx.y;

    const u16* Qb = Q + (size_t)nh * SEQ * DHEAD;
    const u16* Kb = K + (size_t)nh * SEQ * DHEAD;
    const u16* Vb = V + (size_t)nh * SEQ * DHEAD;
    u16*       Ob = O + (size_t)nh * SEQ * DHEAD;

    // stage Q tile (32 x 128) as f32
    for (int v = t; v < 1024; v += 256) {
        int row = v >> 5, c4 = (v & 31) * 4;
        ushort4 u = *(const ushort4*)(Qb + (size_t)(q0 + row) * DHEAD + c4);
        Qs[row][c4 + 0] = bf2f(u.x);
        Qs[row][c4 + 1] = bf2f(u.y);
        Qs[row][c4 + 2] = bf2f(u.z);
        Qs[row][c4 + 3] = bf2f(u.w);
    }

    float m_run[4] = {-1e30f, -1e30f, -1e30f, -1e30f};
    float l_run[4] = {0.f, 0.f, 0.f, 0.f};
    float Oacc[4][4] = {};
    const float scale = 0.08838834764831845f;  // 1/sqrt(128)

    for (int cb = 0; cb < 16; ++cb) {
        __syncthreads();
        int kbase = cb * 32;
        for (int v = t; v < 1024; v += 256) {
            int row = v >> 5, c4 = (v & 31) * 4;
            ushort4 u = *(const ushort4*)(Kb + (size_t)(kbase + row) * DHEAD + c4);
            Kc[row][c4 + 0] = bf2f(u.x);
            Kc[row][c4 + 1] = bf2f(u.y);
            Kc[row][c4 + 2] = bf2f(u.z);
            Kc[row][c4 + 3] = bf2f(u.w);
            ushort4 w2 = *(const ushort4*)(Vb + (size_t)(kbase + row) * DHEAD + c4);
            Vc[row][c4 + 0] = bf2f(w2.x);
            Vc[row][c4 + 1] = bf2f(w2.y);
            Vc[row][c4 + 2] = bf2f(w2.z);
            Vc[row][c4 + 3] = bf2f(w2.w);
        }
        __syncthreads();

        // S chunk: 4 q-rows x 32 k-cols per half-wave, dot length 128
        float s0 = 0.f, s1 = 0.f, s2 = 0.f, s3 = 0.f;
        #pragma unroll
        for (int d4 = 0; d4 < 128; d4 += 4) {
            float4 kv  = *(const float4*)&Kc[k32][d4];
            float4 q0v = *(const float4*)&Qs[qbase + 0][d4];
            float4 q1v = *(const float4*)&Qs[qbase + 1][d4];
            float4 q2v = *(const float4*)&Qs[qbase + 2][d4];
            float4 q3v = *(const float4*)&Qs[qbase + 3][d4];
            s0 += q0v.x * kv.x + q0v.y * kv.y + q0v.z * kv.z + q0v.w * kv.w;
            s1 += q1v.x * kv.x + q1v.y * kv.y + q1v.z * kv.z + q1v.w * kv.w;
            s2 += q2v.x * kv.x + q2v.y * kv.y + q2v.z * kv.z + q2v.w * kv.w;
            s3 += q3v.x * kv.x + q3v.y * kv.y + q3v.z * kv.z + q3v.w * kv.w;
        }
        float sv[4] = {s0 * scale, s1 * scale, s2 * scale, s3 * scale};
        #pragma unroll
        for (int j = 0; j < 4; ++j) {
            float mc = sv[j];
            mc = fmaxf(mc, __shfl_xor(mc, 1));
            mc = fmaxf(mc, __shfl_xor(mc, 2));
            mc = fmaxf(mc, __shfl_xor(mc, 4));
            mc = fmaxf(mc, __shfl_xor(mc, 8));
            mc = fmaxf(mc, __shfl_xor(mc, 16));
            float m_new = fmaxf(m_run[j], mc);
            float alpha = __expf(m_run[j] - m_new);
            float p     = __expf(sv[j] - m_new);
            float rs = p;
            rs += __shfl_xor(rs, 1);
            rs += __shfl_xor(rs, 2);
            rs += __shfl_xor(rs, 4);
            rs += __shfl_xor(rs, 8);
            rs += __shfl_xor(rs, 16);
            l_run[j] = l_run[j] * alpha + rs;
            m_run[j] = m_new;
            Ps[qbase + j][k32] = p;
            #pragma unroll
            for (int c = 0; c < 4; ++c) Oacc[j][c] *= alpha;
        }
        __syncthreads();

        // PV: rows qbase..qbase+3, cols k32*4..+3
        #pragma unroll 4
        for (int kk = 0; kk < 32; ++kk) {
            float4 vv = *(const float4*)&Vc[kk][k32 * 4];
            #pragma unroll
            for (int j = 0; j < 4; ++j) {
                float p = Ps[qbase + j][kk];
                Oacc[j][0] += p * vv.x;
                Oacc[j][1] += p * vv.y;
                Oacc[j][2] += p * vv.z;
                Oacc[j][3] += p * vv.w;
            }
        }
    }

    #pragma unroll
    for (int j = 0; j < 4; ++j) {
        float inv = 1.0f / l_run[j];
        int row = q0 + qbase + j;
        ushort4 st;
        st.x = f2bf(Oacc[j][0] * inv);
        st.y = f2bf(Oacc[j][1] * inv);
        st.z = f2bf(Oacc[j][2] * inv);
        st.w = f2bf(Oacc[j][3] * inv);
        *(ushort4*)(Ob + (size_t)row * DHEAD + k32 * 4) = st;
    }
}

// ---------------------------------------------------------------------------
// 1x1 conv (projection) + residual. Per (n,head): C[co][dd] = Wp[co][:]·O[:][dd]
// then out = x + rw * C, written to d_out (fp32) in [n][c][s] layout.
// ---------------------------------------------------------------------------
__global__ __launch_bounds__(256) void proj_res_kernel(
    const float* __restrict__ Wp,   // [512][512] fp32
    const u16* __restrict__ Oin,    // [32][512][128] bf16
    const float* __restrict__ xres, // [4][512][1024] fp32
    const float* __restrict__ rwp,  // scalar fp32
    float* __restrict__ outp)       // [4][512][1024] fp32
{
    __shared__ float As[16][64];   // Wp tile, k-major: As[ci][co]
    __shared__ float Bs[16][64];   // O tile: Bs[ci][dd]

    const int t   = threadIdx.x;
    const int cob = blockIdx.x;    // 0..7
    const int db  = blockIdx.y;    // 0..1
    const int nh  = blockIdx.z;    // 0..31

    const int b_co = t >> 2, b_kq = t & 3;
    const int l_kk = t >> 4, l_d0 = (t & 15) * 4;
    const int tm = (t & 15) * 4;   // co micro-offset
    const int tn = (t >> 4) * 4;   // dd micro-offset

    float acc[4][4] = {};

    for (int kb = 0; kb < 512; kb += 16) {
        {
            float4 u = *(const float4*)(Wp + (size_t)(cob * 64 + b_co) * 512 + kb + b_kq * 4);
            As[b_kq * 4 + 0][b_co] = u.x;
            As[b_kq * 4 + 1][b_co] = u.y;
            As[b_kq * 4 + 2][b_co] = u.z;
            As[b_kq * 4 + 3][b_co] = u.w;
        }
        {
            ushort4 u = *(const ushort4*)(Oin + (size_t)(nh * 512 + kb + l_kk) * 128 + db * 64 + l_d0);
            Bs[l_kk][l_d0 + 0] = bf2f(u.x);
            Bs[l_kk][l_d0 + 1] = bf2f(u.y);
            Bs[l_kk][l_d0 + 2] = bf2f(u.z);
            Bs[l_kk][l_d0 + 3] = bf2f(u.w);
        }
        __syncthreads();
        #pragma unroll
        for (int kk = 0; kk < 16; ++kk) {
            float4 av = *(const float4*)&As[kk][tm];
            float4 bv = *(const float4*)&Bs[kk][tn];
            float a0[4] = {av.x, av.y, av.z, av.w};
            float b0[4] = {bv.x, bv.y, bv.z, bv.w};
            #pragma unroll
            for (int i = 0; i < 4; ++i)
                #pragma unroll
                for (int j = 0; j < 4; ++j)
                    acc[i][j] += a0[i] * b0[j];
        }
        __syncthreads();
    }

    float rwv = *rwp;
    int n = nh >> 3, head = nh & 7;
    #pragma unroll
    for (int i = 0; i < 4; ++i) {
        int co = cob * 64 + tm + i;
        size_t base = (size_t)(n * 512 + co) * 1024 + head * 128 + db * 64 + tn;
        float4 xr = *(const float4*)(xres + base);
        float4 st;
        st.x = xr.x + rwv * acc[i][0];
        st.y = xr.y + rwv * acc[i][1];
        st.z = xr.z + rwv * acc[i][2];
        st.w = xr.w + rwv * acc[i][3];
        *(float4*)(outp + base) = st;
    }
}

// ---------------------------------------------------------------------------
extern "C" void kernel_launch(void* const* d_in, const int* in_sizes, int n_in,
                              void* d_out, int out_size, void* d_ws, size_t ws_size,
                              hipStream_t stream) {
    const float* x_l = (const float*)d_in[0];
    const float* x_g = (const float*)d_in[1];
    const float* Wk1 = (const float*)d_in[2];
    const float* Wq1 = (const float*)d_in[3];
    const float* Wv1 = (const float*)d_in[4];
    const float* Wk2 = (const float*)d_in[5];
    const float* Wq2 = (const float*)d_in[6];
    const float* Wv2 = (const float*)d_in[7];
    const float* Wp1 = (const float*)d_in[8];
    const float* Wp2 = (const float*)d_in[9];
    const float* rw  = (const float*)d_in[10];

    u16* ws = (u16*)d_ws;
    u16* Kl = ws + (size_t)0 * TSLOT;
    u16* Ql = ws + (size_t)1 * TSLOT;
    u16* Vl = ws + (size_t)2 * TSLOT;
    u16* Kg = ws + (size_t)3 * TSLOT;
    u16* Qg = ws + (size_t)4 * TSLOT;
    u16* Vg = ws + (size_t)5 * TSLOT;
    u16* Og = ws + (size_t)6 * TSLOT;
    u16* Ol = ws + (size_t)7 * TSLOT;

    float* out0 = (float*)d_out;
    float* out1 = out0 + (size_t)TSLOT;

    dim3 cgrid(64, 8);
    conv3x3_kernel<<<cgrid, 256, 0, stream>>>(x_l, Wk1, Kl);
    conv3x3_kernel<<<cgrid, 256, 0, stream>>>(x_l, Wq1, Ql);
    conv3x3_kernel<<<cgrid, 256, 0, stream>>>(x_l, Wv1, Vl);
    conv3x3_kernel<<<cgrid, 256, 0, stream>>>(x_g, Wk2, Kg);
    conv3x3_kernel<<<cgrid, 256, 0, stream>>>(x_g, Wq2, Qg);
    conv3x3_kernel<<<cgrid, 256, 0, stream>>>(x_g, Wv2, Vg);

    dim3 agrid(16, 32);
    // y_g = attend(q_g, k_l, v_l); y_l = attend(q_l, k_g, v_g)
    attn_kernel<<<agrid, 256, 0, stream>>>(Qg, Kl, Vl, Og);
    attn_kernel<<<agrid, 256, 0, stream>>>(Ql, Kg, Vg, Ol);

    dim3 pgrid(8, 2, 32);
    // out0 = x_l + rw * conv1x1(y_l, Wp1); out1 = x_g + rw * conv1x1(y_g, Wp2)
    proj_res_kernel<<<pgrid, 256, 0, stream>>>(Wp1, Ol, x_l, rw, out0);
    proj_res_kernel<<<pgrid, 256, 0, stream>>>(Wp2, Og, x_g, rw, out1);
}

// Round 3
// 1161.991 us; speedup vs baseline: 2.4059x; 2.4059x over previous
//
#include <hip/hip_runtime.h>
#include <stdint.h>

typedef unsigned short u16;
typedef unsigned int u32;

#define N_IMG 4
#define C_CH 512
#define HW_SP 1024
#define NHEAD 8
#define DHEAD 128
#define SEQ 512
#define KCONV 4608                       // C*9
#define TSLOT (N_IMG * NHEAD * SEQ * DHEAD)  // 2097152 elements per tensor

typedef __attribute__((ext_vector_type(8))) short short8;
typedef __attribute__((ext_vector_type(8))) unsigned short u16x8;
typedef __attribute__((ext_vector_type(4))) float f32x4;

__device__ __forceinline__ float bf2f(u16 u) {
    union { u32 i; float f; } v; v.i = ((u32)u) << 16; return v.f;
}
__device__ __forceinline__ u16 f2bf(float f) {
    union { u32 i; float f; } v; v.f = f;
    u32 u = v.i;
    return (u16)((u + 0x7FFFu + ((u >> 16) & 1u)) >> 16);  // RNE
}

// ---------------------------------------------------------------------------
// Fused K/Q/V conv3x3 (pad 1) as MFMA implicit GEMM.
// A = im2col(x): M=4096 (pixel), K=4608. B = W[co][k]: N=1536 (3 tensors x 512).
// Tile 128x128, BK=32, 256 thr, 4 waves x (4x4 of 16x16x32 bf16 MFMA).
// Output bf16, head-split layout [n][head][co][dd]; each m-block of 128 is one
// (n, head) pair, so the 4 acc regs per tile = 4 consecutive dd -> ushort4.
// LDS rows padded to 40 u16: stride 20 dwords -> bank-start period 8 covers
// all 32 banks -> b128 reads/writes at the 8-phase floor.
// ---------------------------------------------------------------------------
__global__ __launch_bounds__(256) void conv3_mfma_kernel(
    const float* __restrict__ x,    // [4][512][32][32] fp32
    const float* __restrict__ w0,   // [512][4608] fp32 (Wk)
    const float* __restrict__ w1,   // (Wq)
    const float* __restrict__ w2,   // (Wv)
    u16* __restrict__ o0,           // [4][8][512][128] bf16 (K)
    u16* __restrict__ o1,           // (Q)
    u16* __restrict__ o2)           // (V)
{
    __shared__ u16 A_lds[128][40];
    __shared__ u16 B_lds[128][40];

    const int t  = threadIdx.x;
    const int m0 = blockIdx.x * 128;       // 0..4095, one (n,head) per block
    const int by = blockIdx.y;             // 0..11
    const int wt = by >> 2;                // which weight/output tensor
    const int co_base = (by & 3) * 128;

    const float* wsel = (wt == 0) ? w0 : (wt == 1) ? w1 : w2;
    u16*         osel = (wt == 0) ? o0 : (wt == 1) ? o1 : o2;

    const int n_img  = m0 >> 10;
    const int head   = (m0 & 1023) >> 7;
    const int s_base = m0 & 1023;

    // staging roles
    const int m_idx = t & 127;             // row (A: m, B: co)
    const int khalf = t >> 7;              // which 16-k half of BK=32
    const int s  = s_base + m_idx;
    const int y  = s >> 5;
    const int xs = s & 31;
    const float* xbase = x + (size_t)n_img * 512 * 1024;
    const float* wrow  = wsel + (size_t)(co_base + m_idx) * KCONV;

    // compute roles
    const int lane = t & 63;
    const int wv   = t >> 6;
    const int wm   = (wv & 1) * 64;
    const int wn   = (wv >> 1) * 64;
    const int frow = lane & 15;
    const int koff = (lane >> 4) * 8;

    f32x4 acc[4][4] = {};

    for (int kb = 0; kb < KCONV; kb += 32) {
        // ---- stage A: im2col gather, 16 elems/thread (2 chunks of 8) ----
        {
            int kk = kb + khalf * 16;
            int ci = kk / 9;
            int r  = kk - ci * 9;
            int ky = r / 3;
            int kx = r - ky * 3;
            #pragma unroll
            for (int c = 0; c < 2; ++c) {
                u16x8 va;
                #pragma unroll
                for (int j = 0; j < 8; ++j) {
                    int yy = y + ky - 1;
                    int xx = xs + kx - 1;
                    float v = 0.0f;
                    if ((unsigned)yy < 32u && (unsigned)xx < 32u)
                        v = xbase[ci * 1024 + yy * 32 + xx];
                    va[j] = f2bf(v);
                    if (++kx == 3) { kx = 0; if (++ky == 3) { ky = 0; ++ci; } }
                }
                *(u16x8*)&A_lds[m_idx][khalf * 16 + c * 8] = va;
            }
        }
        // ---- stage B: weights, contiguous k ----
        {
            const float4* wp = (const float4*)(wrow + kb + khalf * 16);
            float4 a0 = wp[0], a1 = wp[1], a2 = wp[2], a3 = wp[3];
            u16x8 vb;
            vb[0] = f2bf(a0.x); vb[1] = f2bf(a0.y); vb[2] = f2bf(a0.z); vb[3] = f2bf(a0.w);
            vb[4] = f2bf(a1.x); vb[5] = f2bf(a1.y); vb[6] = f2bf(a1.z); vb[7] = f2bf(a1.w);
            *(u16x8*)&B_lds[m_idx][khalf * 16 + 0] = vb;
            vb[0] = f2bf(a2.x); vb[1] = f2bf(a2.y); vb[2] = f2bf(a2.z); vb[3] = f2bf(a2.w);
            vb[4] = f2bf(a3.x); vb[5] = f2bf(a3.y); vb[6] = f2bf(a3.z); vb[7] = f2bf(a3.w);
            *(u16x8*)&B_lds[m_idx][khalf * 16 + 8] = vb;
        }
        __syncthreads();

        short8 a_frag[4], b_frag[4];
        #pragma unroll
        for (int i = 0; i < 4; ++i)
            a_frag[i] = *(const short8*)&A_lds[wm + i * 16 + frow][koff];
        #pragma unroll
        for (int j = 0; j < 4; ++j)
            b_frag[j] = *(const short8*)&B_lds[wn + j * 16 + frow][koff];
        #pragma unroll
        for (int i = 0; i < 4; ++i)
            #pragma unroll
            for (int j = 0; j < 4; ++j)
                acc[i][j] = __builtin_amdgcn_mfma_f32_16x16x32_bf16(
                    a_frag[i], b_frag[j], acc[i][j], 0, 0, 0);
        __syncthreads();
    }

    // epilogue: D mapping col=lane&15 (co), row=(lane>>4)*4+reg (m -> dd)
    u16* obase = osel + (size_t)(n_img * 8 + head) * 512 * 128;
    #pragma unroll
    for (int i = 0; i < 4; ++i) {
        int dd0 = wm + i * 16 + (lane >> 4) * 4;
        #pragma unroll
        for (int j = 0; j < 4; ++j) {
            int co = co_base + wn + j * 16 + frow;
            ushort4 st;
            st.x = f2bf(acc[i][j][0]);
            st.y = f2bf(acc[i][j][1]);
            st.z = f2bf(acc[i][j][2]);
            st.w = f2bf(acc[i][j][3]);
            *(ushort4*)(obase + (size_t)co * 128 + dd0) = st;
        }
    }
}

// ---------------------------------------------------------------------------
// Flash-style attention, fp32 math, bf16 I/O (workspace tensors).
// ---------------------------------------------------------------------------
__global__ __launch_bounds__(256) void attn_kernel(
    const u16* __restrict__ Q,   // [32][512][128]
    const u16* __restrict__ K,
    const u16* __restrict__ V,
    u16* __restrict__ O)
{
    __shared__ float Qs[32][132];
    __shared__ float Kc[32][132];
    __shared__ float Vc[32][128];
    __shared__ float Ps[32][33];

    const int t     = threadIdx.x;
    const int lane  = t & 63;
    const int wave  = t >> 6;
    const int k32   = lane & 31;
    const int qbase = wave * 8 + (lane >> 5) * 4;
    const int q0    = blockIdx.x * 32;
    const int nh    = blockIdx.y;

    const u16* Qb = Q + (size_t)nh * SEQ * DHEAD;
    const u16* Kb = K + (size_t)nh * SEQ * DHEAD;
    const u16* Vb = V + (size_t)nh * SEQ * DHEAD;
    u16*       Ob = O + (size_t)nh * SEQ * DHEAD;

    for (int v = t; v < 1024; v += 256) {
        int row = v >> 5, c4 = (v & 31) * 4;
        ushort4 u = *(const ushort4*)(Qb + (size_t)(q0 + row) * DHEAD + c4);
        Qs[row][c4 + 0] = bf2f(u.x);
        Qs[row][c4 + 1] = bf2f(u.y);
        Qs[row][c4 + 2] = bf2f(u.z);
        Qs[row][c4 + 3] = bf2f(u.w);
    }

    float m_run[4] = {-1e30f, -1e30f, -1e30f, -1e30f};
    float l_run[4] = {0.f, 0.f, 0.f, 0.f};
    float Oacc[4][4] = {};
    const float scale = 0.08838834764831845f;  // 1/sqrt(128)

    for (int cb = 0; cb < 16; ++cb) {
        __syncthreads();
        int kbase = cb * 32;
        for (int v = t; v < 1024; v += 256) {
            int row = v >> 5, c4 = (v & 31) * 4;
            ushort4 u = *(const ushort4*)(Kb + (size_t)(kbase + row) * DHEAD + c4);
            Kc[row][c4 + 0] = bf2f(u.x);
            Kc[row][c4 + 1] = bf2f(u.y);
            Kc[row][c4 + 2] = bf2f(u.z);
            Kc[row][c4 + 3] = bf2f(u.w);
            ushort4 w2 = *(const ushort4*)(Vb + (size_t)(kbase + row) * DHEAD + c4);
            Vc[row][c4 + 0] = bf2f(w2.x);
            Vc[row][c4 + 1] = bf2f(w2.y);
            Vc[row][c4 + 2] = bf2f(w2.z);
            Vc[row][c4 + 3] = bf2f(w2.w);
        }
        __syncthreads();

        float s0 = 0.f, s1 = 0.f, s2 = 0.f, s3 = 0.f;
        #pragma unroll
        for (int d4 = 0; d4 < 128; d4 += 4) {
            float4 kv  = *(const float4*)&Kc[k32][d4];
            float4 q0v = *(const float4*)&Qs[qbase + 0][d4];
            float4 q1v = *(const float4*)&Qs[qbase + 1][d4];
            float4 q2v = *(const float4*)&Qs[qbase + 2][d4];
            float4 q3v = *(const float4*)&Qs[qbase + 3][d4];
            s0 += q0v.x * kv.x + q0v.y * kv.y + q0v.z * kv.z + q0v.w * kv.w;
            s1 += q1v.x * kv.x + q1v.y * kv.y + q1v.z * kv.z + q1v.w * kv.w;
            s2 += q2v.x * kv.x + q2v.y * kv.y + q2v.z * kv.z + q2v.w * kv.w;
            s3 += q3v.x * kv.x + q3v.y * kv.y + q3v.z * kv.z + q3v.w * kv.w;
        }
        float sv[4] = {s0 * scale, s1 * scale, s2 * scale, s3 * scale};
        #pragma unroll
        for (int j = 0; j < 4; ++j) {
            float mc = sv[j];
            mc = fmaxf(mc, __shfl_xor(mc, 1));
            mc = fmaxf(mc, __shfl_xor(mc, 2));
            mc = fmaxf(mc, __shfl_xor(mc, 4));
            mc = fmaxf(mc, __shfl_xor(mc, 8));
            mc = fmaxf(mc, __shfl_xor(mc, 16));
            float m_new = fmaxf(m_run[j], mc);
            float alpha = __expf(m_run[j] - m_new);
            float p     = __expf(sv[j] - m_new);
            float rs = p;
            rs += __shfl_xor(rs, 1);
            rs += __shfl_xor(rs, 2);
            rs += __shfl_xor(rs, 4);
            rs += __shfl_xor(rs, 8);
            rs += __shfl_xor(rs, 16);
            l_run[j] = l_run[j] * alpha + rs;
            m_run[j] = m_new;
            Ps[qbase + j][k32] = p;
            #pragma unroll
            for (int c = 0; c < 4; ++c) Oacc[j][c] *= alpha;
        }
        __syncthreads();

        #pragma unroll 4
        for (int kk = 0; kk < 32; ++kk) {
            float4 vv = *(const float4*)&Vc[kk][k32 * 4];
            #pragma unroll
            for (int j = 0; j < 4; ++j) {
                float p = Ps[qbase + j][kk];
                Oacc[j][0] += p * vv.x;
                Oacc[j][1] += p * vv.y;
                Oacc[j][2] += p * vv.z;
                Oacc[j][3] += p * vv.w;
            }
        }
    }

    #pragma unroll
    for (int j = 0; j < 4; ++j) {
        float inv = 1.0f / l_run[j];
        int row = q0 + qbase + j;
        ushort4 st;
        st.x = f2bf(Oacc[j][0] * inv);
        st.y = f2bf(Oacc[j][1] * inv);
        st.z = f2bf(Oacc[j][2] * inv);
        st.w = f2bf(Oacc[j][3] * inv);
        *(ushort4*)(Ob + (size_t)row * DHEAD + k32 * 4) = st;
    }
}

// ---------------------------------------------------------------------------
// 1x1 conv (projection) + residual, fp32 out.
// ---------------------------------------------------------------------------
__global__ __launch_bounds__(256) void proj_res_kernel(
    const float* __restrict__ Wp,   // [512][512] fp32
    const u16* __restrict__ Oin,    // [32][512][128] bf16
    const float* __restrict__ xres, // [4][512][1024] fp32
    const float* __restrict__ rwp,  // scalar fp32
    float* __restrict__ outp)       // [4][512][1024] fp32
{
    __shared__ float As[16][64];
    __shared__ float Bs[16][64];

    const int t   = threadIdx.x;
    const int cob = blockIdx.x;
    const int db  = blockIdx.y;
    const int nh  = blockIdx.z;

    const int b_co = t >> 2, b_kq = t & 3;
    const int l_kk = t >> 4, l_d0 = (t & 15) * 4;
    const int tm = (t & 15) * 4;
    const int tn = (t >> 4) * 4;

    float acc[4][4] = {};

    for (int kb = 0; kb < 512; kb += 16) {
        {
            float4 u = *(const float4*)(Wp + (size_t)(cob * 64 + b_co) * 512 + kb + b_kq * 4);
            As[b_kq * 4 + 0][b_co] = u.x;
            As[b_kq * 4 + 1][b_co] = u.y;
            As[b_kq * 4 + 2][b_co] = u.z;
            As[b_kq * 4 + 3][b_co] = u.w;
        }
        {
            ushort4 u = *(const ushort4*)(Oin + (size_t)(nh * 512 + kb + l_kk) * 128 + db * 64 + l_d0);
            Bs[l_kk][l_d0 + 0] = bf2f(u.x);
            Bs[l_kk][l_d0 + 1] = bf2f(u.y);
            Bs[l_kk][l_d0 + 2] = bf2f(u.z);
            Bs[l_kk][l_d0 + 3] = bf2f(u.w);
        }
        __syncthreads();
        #pragma unroll
        for (int kk = 0; kk < 16; ++kk) {
            float4 av = *(const float4*)&As[kk][tm];
            float4 bv = *(const float4*)&Bs[kk][tn];
            float a0[4] = {av.x, av.y, av.z, av.w};
            float b0[4] = {bv.x, bv.y, bv.z, bv.w};
            #pragma unroll
            for (int i = 0; i < 4; ++i)
                #pragma unroll
                for (int j = 0; j < 4; ++j)
                    acc[i][j] += a0[i] * b0[j];
        }
        __syncthreads();
    }

    float rwv = *rwp;
    int n = nh >> 3, head = nh & 7;
    #pragma unroll
    for (int i = 0; i < 4; ++i) {
        int co = cob * 64 + tm + i;
        size_t base = (size_t)(n * 512 + co) * 1024 + head * 128 + db * 64 + tn;
        float4 xr = *(const float4*)(xres + base);
        float4 st;
        st.x = xr.x + rwv * acc[i][0];
        st.y = xr.y + rwv * acc[i][1];
        st.z = xr.z + rwv * acc[i][2];
        st.w = xr.w + rwv * acc[i][3];
        *(float4*)(outp + base) = st;
    }
}

// ---------------------------------------------------------------------------
extern "C" void kernel_launch(void* const* d_in, const int* in_sizes, int n_in,
                              void* d_out, int out_size, void* d_ws, size_t ws_size,
                              hipStream_t stream) {
    const float* x_l = (const float*)d_in[0];
    const float* x_g = (const float*)d_in[1];
    const float* Wk1 = (const float*)d_in[2];
    const float* Wq1 = (const float*)d_in[3];
    const float* Wv1 = (const float*)d_in[4];
    const float* Wk2 = (const float*)d_in[5];
    const float* Wq2 = (const float*)d_in[6];
    const float* Wv2 = (const float*)d_in[7];
    const float* Wp1 = (const float*)d_in[8];
    const float* Wp2 = (const float*)d_in[9];
    const float* rw  = (const float*)d_in[10];

    u16* ws = (u16*)d_ws;
    u16* Kl = ws + (size_t)0 * TSLOT;
    u16* Ql = ws + (size_t)1 * TSLOT;
    u16* Vl = ws + (size_t)2 * TSLOT;
    u16* Kg = ws + (size_t)3 * TSLOT;
    u16* Qg = ws + (size_t)4 * TSLOT;
    u16* Vg = ws + (size_t)5 * TSLOT;
    u16* Og = ws + (size_t)6 * TSLOT;
    u16* Ol = ws + (size_t)7 * TSLOT;

    float* out0 = (float*)d_out;
    float* out1 = out0 + (size_t)TSLOT;

    dim3 cgrid(32, 12);
    conv3_mfma_kernel<<<cgrid, 256, 0, stream>>>(x_l, Wk1, Wq1, Wv1, Kl, Ql, Vl);
    conv3_mfma_kernel<<<cgrid, 256, 0, stream>>>(x_g, Wk2, Wq2, Wv2, Kg, Qg, Vg);

    dim3 agrid(16, 32);
    attn_kernel<<<agrid, 256, 0, stream>>>(Qg, Kl, Vl, Og);
    attn_kernel<<<agrid, 256, 0, stream>>>(Ql, Kg, Vg, Ol);

    dim3 pgrid(8, 2, 32);
    proj_res_kernel<<<pgrid, 256, 0, stream>>>(Wp1, Ol, x_l, rw, out0);
    proj_res_kernel<<<pgrid, 256, 0, stream>>>(Wp2, Og, x_g, rw, out1);
}

// Round 4
// 688.575 us; speedup vs baseline: 4.0601x; 1.6875x over previous
//
#include <hip/hip_runtime.h>
#include <hip/hip_bf16.h>
#include <stdint.h>

typedef unsigned short u16;
typedef unsigned int u32;

#define TSLOT 2097152            // elements per [4][8][512][128] tensor
#define IC_ELEMS 37748736ull     // 8192 x 4608

typedef __attribute__((ext_vector_type(8))) short short8;
typedef __attribute__((ext_vector_type(8))) unsigned short u16x8;
typedef __attribute__((ext_vector_type(4))) float f32x4;

__device__ __forceinline__ float bf2f(u16 u) {
    union { u32 i; float f; } v; v.i = ((u32)u) << 16; return v.f;
}
__device__ __forceinline__ u16 f2bf(float f) {
    union { u32 i; float f; } v; v.f = f;
    u32 u = v.i;
    return (u16)((u + 0x7FFFu + ((u >> 16) & 1u)) >> 16);  // RNE
}
__device__ __forceinline__ u32 pkbf(float a, float b) {
    __hip_bfloat162 h = __float22bfloat162_rn(make_float2(a, b));
    u32 u; __builtin_memcpy(&u, &h, 4); return u;
}

// ---------------------------------------------------------------------------
// im2col materialization: ic[m][k] bf16, m = img*4096 + n*1024 + y*32 + x,
// k = ci*9 + ky*3 + kx  (matches OIHW weight flattening).
// Block: 64 m (2 image rows) x 32 ci -> 288 k. LDS-staged for coalescing.
// ---------------------------------------------------------------------------
__global__ __launch_bounds__(256) void im2col_prep(
    const float* __restrict__ xl, const float* __restrict__ xg,
    u16* __restrict__ ic)
{
    __shared__ float xs[32][4][32];   // [ci_local][y0-1..y0+2][x]

    const int t  = threadIdx.x;
    const int mt = blockIdx.x;        // 0..127
    const int ct = blockIdx.y;        // 0..15
    const int m0 = mt * 64;
    const int img  = m0 >> 12;
    const int m_in = m0 & 4095;
    const int n_i  = m_in >> 10;
    const int y0   = (m_in & 1023) >> 5;

    const float* xp = (img ? xg : xl) + ((size_t)n_i * 512 + ct * 32) * 1024;

    for (int v = t; v < 4096; v += 256) {
        int ci = v >> 7;
        int r  = (v >> 5) & 3;
        int xx = v & 31;
        int yy = y0 - 1 + r;
        xs[ci][r][xx] = ((unsigned)yy < 32u) ? xp[ci * 1024 + yy * 32 + xx] : 0.f;
    }
    __syncthreads();

    const int m_local = t >> 2;        // 0..63
    const int q       = t & 3;         // 8-ci group
    const int y_sel   = m_local >> 5;  // 0/1
    const int x       = m_local & 31;
    u16* orow = ic + (size_t)(m0 + m_local) * 4608 + (size_t)(ct * 32 + q * 8) * 9;

    #pragma unroll
    for (int c = 0; c < 9; ++c) {      // 9 chunks of 8 k-values (72 total)
        u16x8 st;
        #pragma unroll
        for (int u = 0; u < 8; ++u) {
            const int e   = c * 8 + u;       // 0..71, compile-time
            const int cil = q * 8 + e / 9;
            const int tap = e % 9;
            const int ky  = tap / 3, kx = tap % 3;
            int xx = x + kx - 1;
            float v = ((unsigned)xx < 32u) ? xs[cil][y_sel + ky][xx] : 0.f;
            st[u] = f2bf(v);
        }
        *(u16x8*)(orow + c * 8) = st;
    }
}

// ---------------------------------------------------------------------------
// Conv as clean GEMM: C[m][co] = ic[m][:] . W[co][:], K=4608, BK=32.
// 128x128 tile, 4 waves x (4x4 of 16x16x32 bf16). Grid (64 mtiles, 12 ntiles):
// img = mt>>5; nt -> (tensor K/Q/V, co block). K,Q written [n][head][co][dd];
// V written transposed [n][head][dd][co] for the attention/proj pipeline.
// ---------------------------------------------------------------------------
__global__ __launch_bounds__(256) void conv_gemm(
    const u16* __restrict__ ic,
    const float* __restrict__ wk1, const float* __restrict__ wq1, const float* __restrict__ wv1,
    const float* __restrict__ wk2, const float* __restrict__ wq2, const float* __restrict__ wv2,
    u16* __restrict__ kl, u16* __restrict__ ql, u16* __restrict__ vl,
    u16* __restrict__ kg, u16* __restrict__ qg, u16* __restrict__ vg)
{
    __shared__ u16 A_lds[128][40];
    __shared__ u16 B_lds[128][40];

    const int t  = threadIdx.x;
    const int mt = blockIdx.x;   // 0..63
    const int nt = blockIdx.y;   // 0..11
    const int img = mt >> 5;
    const int wt  = nt >> 2;
    const int co0 = (nt & 3) * 128;
    const int m0  = mt * 128;

    const float* wsel = img == 0 ? (wt == 0 ? wk1 : wt == 1 ? wq1 : wv1)
                                 : (wt == 0 ? wk2 : wt == 1 ? wq2 : wv2);
    u16* osel = img == 0 ? (wt == 0 ? kl : wt == 1 ? ql : vl)
                         : (wt == 0 ? kg : wt == 1 ? qg : vg);

    const int row  = t & 127;
    const int half = t >> 7;
    const u16*   arow = ic   + (size_t)(m0 + row) * 4608 + half * 16;
    const float* wrow = wsel + (size_t)(co0 + row) * 4608 + half * 16;

    const int lane = t & 63;
    const int wv4  = t >> 6;
    const int wm   = (wv4 & 1) * 64;
    const int wn   = (wv4 >> 1) * 64;
    const int fr   = lane & 15;
    const int koq  = (lane >> 4) * 8;

    f32x4 acc[4][4] = {};

    for (int kb = 0; kb < 4608; kb += 32) {
        __syncthreads();
        *(u16x8*)&A_lds[row][half * 16]     = *(const u16x8*)(arow + kb);
        *(u16x8*)&A_lds[row][half * 16 + 8] = *(const u16x8*)(arow + kb + 8);
        {
            const float4* wp4 = (const float4*)(wrow + kb);
            float4 f0 = wp4[0], f1 = wp4[1], f2 = wp4[2], f3 = wp4[3];
            u32 p[4];
            p[0] = pkbf(f0.x, f0.y); p[1] = pkbf(f0.z, f0.w);
            p[2] = pkbf(f1.x, f1.y); p[3] = pkbf(f1.z, f1.w);
            *(uint4*)&B_lds[row][half * 16] = *(uint4*)p;
            p[0] = pkbf(f2.x, f2.y); p[1] = pkbf(f2.z, f2.w);
            p[2] = pkbf(f3.x, f3.y); p[3] = pkbf(f3.z, f3.w);
            *(uint4*)&B_lds[row][half * 16 + 8] = *(uint4*)p;
        }
        __syncthreads();
        short8 af[4], bf[4];
        #pragma unroll
        for (int i = 0; i < 4; ++i) af[i] = *(const short8*)&A_lds[wm + i * 16 + fr][koq];
        #pragma unroll
        for (int j = 0; j < 4; ++j) bf[j] = *(const short8*)&B_lds[wn + j * 16 + fr][koq];
        #pragma unroll
        for (int i = 0; i < 4; ++i)
            #pragma unroll
            for (int j = 0; j < 4; ++j)
                acc[i][j] = __builtin_amdgcn_mfma_f32_16x16x32_bf16(af[i], bf[j], acc[i][j], 0, 0, 0);
    }

    const int m_in = m0 & 4095;
    const int n_i  = m_in >> 10;
    const int head = (m_in & 1023) >> 7;
    u16* ob = osel + (size_t)(n_i * 8 + head) * 65536;
    if (wt == 2) {
        // V transposed: [dd][co]
        #pragma unroll
        for (int i = 0; i < 4; ++i) {
            int dd0 = wm + i * 16 + (lane >> 4) * 4;
            #pragma unroll
            for (int j = 0; j < 4; ++j) {
                int co = co0 + wn + j * 16 + fr;
                #pragma unroll
                for (int r = 0; r < 4; ++r)
                    ob[(size_t)(dd0 + r) * 512 + co] = f2bf(acc[i][j][r]);
            }
        }
    } else {
        #pragma unroll
        for (int i = 0; i < 4; ++i) {
            int dd0 = wm + i * 16 + (lane >> 4) * 4;
            #pragma unroll
            for (int j = 0; j < 4; ++j) {
                int co = co0 + wn + j * 16 + fr;
                ushort4 st;
                st.x = f2bf(acc[i][j][0]); st.y = f2bf(acc[i][j][1]);
                st.z = f2bf(acc[i][j][2]); st.w = f2bf(acc[i][j][3]);
                *(ushort4*)(ob + (size_t)co * 128 + dd0) = st;
            }
        }
    }
}

// ---------------------------------------------------------------------------
// MFMA flash attention. Q,K: [nh][c=512][d=128]; V pre-transposed [nh][d][c].
// Block = (q-tile 64, nh, which). Wave w owns q rows w*16..+15.
// S = Q.K^T via mfma(A=Q, B=K); softmax state in row-layout registers;
// P round-trips LDS (C-layout -> B-layout, same-wave); O^T += V^T.P^T via
// mfma(A=V^T, B=P) so the output lands as O^T[d][q] -> [s][c] for proj.
// ---------------------------------------------------------------------------
__global__ __launch_bounds__(256) void attn_mfma(
    const u16* __restrict__ Q0, const u16* __restrict__ K0,
    const u16* __restrict__ V0, u16* __restrict__ O0,
    const u16* __restrict__ Q1, const u16* __restrict__ K1,
    const u16* __restrict__ V1, u16* __restrict__ O1)
{
    __shared__ u16 Qs[64][136];
    __shared__ u16 Ks[64][136];
    __shared__ u16 Vs[128][72];
    __shared__ u16 Ps[64][72];

    const int t    = threadIdx.x;
    const int lane = t & 63;
    const int w    = t >> 6;
    const int qt   = blockIdx.x;   // 0..7
    const int nh   = blockIdx.y;   // 0..31
    const int z    = blockIdx.z;   // 0..1

    const u16* Q = (z ? Q1 : Q0) + (size_t)nh * 65536;
    const u16* K = (z ? K1 : K0) + (size_t)nh * 65536;
    const u16* V = (z ? V1 : V0) + (size_t)nh * 65536;
    u16*       O = (z ? O1 : O0) + (size_t)nh * 65536;

    const int q0 = qt * 64;
    for (int v = t; v < 1024; v += 256) {
        int row = v >> 4, c8 = (v & 15) * 8;
        *(u16x8*)&Qs[row][c8] = *(const u16x8*)(Q + (size_t)(q0 + row) * 128 + c8);
    }

    const int fr  = lane & 15;
    const int qd  = lane >> 4;
    const int koq = qd * 8;

    float m_run[4] = {-3e38f, -3e38f, -3e38f, -3e38f};
    float l_run[4] = {0.f, 0.f, 0.f, 0.f};
    f32x4 Ot[8] = {};
    const float scale = 0.08838834764831845f;   // 1/sqrt(128)

    for (int cb = 0; cb < 8; ++cb) {
        __syncthreads();   // prev S (Ks) and PV (Vs) done
        const int kb = cb * 64;
        for (int v = t; v < 1024; v += 256) {
            int row = v >> 4, c8 = (v & 15) * 8;
            *(u16x8*)&Ks[row][c8] = *(const u16x8*)(K + (size_t)(kb + row) * 128 + c8);
        }
        for (int v = t; v < 1024; v += 256) {
            int row = v >> 3, c8 = (v & 7) * 8;
            *(u16x8*)&Vs[row][c8] = *(const u16x8*)(V + (size_t)row * 512 + kb + c8);
        }
        __syncthreads();

        // S: 16 q-rows x 64 k-cols per wave
        f32x4 s[4] = {};
        #pragma unroll
        for (int dstep = 0; dstep < 4; ++dstep) {
            short8 a = *(const short8*)&Qs[w * 16 + fr][dstep * 32 + koq];
            #pragma unroll
            for (int nj = 0; nj < 4; ++nj) {
                short8 b = *(const short8*)&Ks[nj * 16 + fr][dstep * 32 + koq];
                s[nj] = __builtin_amdgcn_mfma_f32_16x16x32_bf16(a, b, s[nj], 0, 0, 0);
            }
        }

        // online softmax, row-layout (row = qd*4+r within wave's 16)
        float al[4];
        #pragma unroll
        for (int r = 0; r < 4; ++r) {
            float mc = fmaxf(fmaxf(s[0][r], s[1][r]), fmaxf(s[2][r], s[3][r])) * scale;
            mc = fmaxf(mc, __shfl_xor(mc, 1));
            mc = fmaxf(mc, __shfl_xor(mc, 2));
            mc = fmaxf(mc, __shfl_xor(mc, 4));
            mc = fmaxf(mc, __shfl_xor(mc, 8));
            float mn = fmaxf(m_run[r], mc);
            al[r] = __expf(m_run[r] - mn);
            m_run[r] = mn;
            float rs = 0.f;
            #pragma unroll
            for (int nj = 0; nj < 4; ++nj) {
                float p = __expf(s[nj][r] * scale - mn);
                s[nj][r] = p;
                rs += p;
            }
            rs += __shfl_xor(rs, 1);
            rs += __shfl_xor(rs, 2);
            rs += __shfl_xor(rs, 4);
            rs += __shfl_xor(rs, 8);
            l_run[r] = l_run[r] * al[r] + rs;
        }

        // P -> LDS (wave-private rows; same-wave read below)
        #pragma unroll
        for (int nj = 0; nj < 4; ++nj)
            #pragma unroll
            for (int r = 0; r < 4; ++r)
                Ps[w * 16 + qd * 4 + r][nj * 16 + fr] = f2bf(s[nj][r]);

        // alpha to column layout (q = fr)
        {
            int srcl = (fr >> 2) << 4;
            float a0 = __shfl(al[0], srcl), a1 = __shfl(al[1], srcl);
            float a2 = __shfl(al[2], srcl), a3 = __shfl(al[3], srcl);
            int rsel = fr & 3;
            float ac = rsel == 0 ? a0 : rsel == 1 ? a1 : rsel == 2 ? a2 : a3;
            #pragma unroll
            for (int t8 = 0; t8 < 8; ++t8)
                #pragma unroll
                for (int r = 0; r < 4; ++r)
                    Ot[t8][r] *= ac;
        }

        // PV: O^T[128 d][16 q] += V^T . P^T
        #pragma unroll
        for (int ks = 0; ks < 2; ++ks) {
            short8 b = *(const short8*)&Ps[w * 16 + fr][ks * 32 + koq];
            #pragma unroll
            for (int t8 = 0; t8 < 8; ++t8) {
                short8 a = *(const short8*)&Vs[t8 * 16 + fr][ks * 32 + koq];
                Ot[t8] = __builtin_amdgcn_mfma_f32_16x16x32_bf16(a, b, Ot[t8], 0, 0, 0);
            }
        }
    }

    // epilogue: 1/l in column layout, write O^T[d][c]
    int srcl = (fr >> 2) << 4;
    float l0 = __shfl(l_run[0], srcl), l1 = __shfl(l_run[1], srcl);
    float l2 = __shfl(l_run[2], srcl), l3 = __shfl(l_run[3], srcl);
    int rsel = fr & 3;
    float lc = rsel == 0 ? l0 : rsel == 1 ? l1 : rsel == 2 ? l2 : l3;
    float linv = 1.0f / lc;
    int c = q0 + w * 16 + fr;
    #pragma unroll
    for (int t8 = 0; t8 < 8; ++t8)
        #pragma unroll
        for (int r = 0; r < 4; ++r) {
            int d = t8 * 16 + qd * 4 + r;
            O[(size_t)d * 512 + c] = f2bf(Ot[t8][r] * linv);
        }
}

// ---------------------------------------------------------------------------
// Projection GEMM + residual: out[n][co][s] = x + rw * sum_ci Wp[co][ci] Ot[s][ci]
// A = Wp (fp32->bf16 staged), B = Ot rows s (k=ci contiguous). 128x128, BK=32.
// ---------------------------------------------------------------------------
__global__ __launch_bounds__(256) void proj_mfma(
    const float* __restrict__ Wp1, const float* __restrict__ Wp2,
    const u16* __restrict__ Otl, const u16* __restrict__ Otg,
    const float* __restrict__ x_l, const float* __restrict__ x_g,
    const float* __restrict__ rwp,
    float* __restrict__ out0, float* __restrict__ out1)
{
    __shared__ u16 A_lds[128][40];
    __shared__ u16 B_lds[128][40];

    const int t  = threadIdx.x;
    const int ct = blockIdx.x;        // co tile 0..3
    const int st = blockIdx.y;        // s tile 0..7
    const int z  = blockIdx.z;        // which*4 + nn
    const int which = z >> 2;
    const int nn    = z & 3;

    const float* Wp = which ? Wp2 : Wp1;
    const u16*   Ot = (which ? Otg : Otl) + (size_t)nn * 524288;
    const float* xr = (which ? x_g : x_l) + (size_t)nn * 524288;
    float*     outp = (which ? out1 : out0) + (size_t)nn * 524288;

    const int co0 = ct * 128, s0 = st * 128;
    const int row = t & 127, half = t >> 7;
    const float* wrow = Wp + (size_t)(co0 + row) * 512 + half * 16;
    const u16*   brow = Ot + (size_t)(s0 + row) * 512 + half * 16;

    const int lane = t & 63;
    const int wv4  = t >> 6;
    const int wm   = (wv4 & 1) * 64;
    const int wn   = (wv4 >> 1) * 64;
    const int fr   = lane & 15;
    const int koq  = (lane >> 4) * 8;

    f32x4 acc[4][4] = {};

    for (int kb = 0; kb < 512; kb += 32) {
        __syncthreads();
        {
            const float4* wp4 = (const float4*)(wrow + kb);
            float4 f0 = wp4[0], f1 = wp4[1], f2 = wp4[2], f3 = wp4[3];
            u32 p[4];
            p[0] = pkbf(f0.x, f0.y); p[1] = pkbf(f0.z, f0.w);
            p[2] = pkbf(f1.x, f1.y); p[3] = pkbf(f1.z, f1.w);
            *(uint4*)&A_lds[row][half * 16] = *(uint4*)p;
            p[0] = pkbf(f2.x, f2.y); p[1] = pkbf(f2.z, f2.w);
            p[2] = pkbf(f3.x, f3.y); p[3] = pkbf(f3.z, f3.w);
            *(uint4*)&A_lds[row][half * 16 + 8] = *(uint4*)p;
        }
        *(u16x8*)&B_lds[row][half * 16]     = *(const u16x8*)(brow + kb);
        *(u16x8*)&B_lds[row][half * 16 + 8] = *(const u16x8*)(brow + kb + 8);
        __syncthreads();
        short8 af[4], bf[4];
        #pragma unroll
        for (int i = 0; i < 4; ++i) af[i] = *(const short8*)&A_lds[wm + i * 16 + fr][koq];
        #pragma unroll
        for (int j = 0; j < 4; ++j) bf[j] = *(const short8*)&B_lds[wn + j * 16 + fr][koq];
        #pragma unroll
        for (int i = 0; i < 4; ++i)
            #pragma unroll
            for (int j = 0; j < 4; ++j)
                acc[i][j] = __builtin_amdgcn_mfma_f32_16x16x32_bf16(af[i], bf[j], acc[i][j], 0, 0, 0);
    }

    const float rwv = *rwp;
    #pragma unroll
    for (int i = 0; i < 4; ++i) {
        int co_b = co0 + wm + i * 16 + (lane >> 4) * 4;
        #pragma unroll
        for (int j = 0; j < 4; ++j) {
            int s = s0 + wn + j * 16 + fr;
            #pragma unroll
            for (int r = 0; r < 4; ++r) {
                size_t a = (size_t)(co_b + r) * 1024 + s;
                outp[a] = xr[a] + rwv * acc[i][j][r];
            }
        }
    }
}

// ---------------------------------------------------------------------------
extern "C" void kernel_launch(void* const* d_in, const int* in_sizes, int n_in,
                              void* d_out, int out_size, void* d_ws, size_t ws_size,
                              hipStream_t stream) {
    const float* x_l = (const float*)d_in[0];
    const float* x_g = (const float*)d_in[1];
    const float* Wk1 = (const float*)d_in[2];
    const float* Wq1 = (const float*)d_in[3];
    const float* Wv1 = (const float*)d_in[4];
    const float* Wk2 = (const float*)d_in[5];
    const float* Wq2 = (const float*)d_in[6];
    const float* Wv2 = (const float*)d_in[7];
    const float* Wp1 = (const float*)d_in[8];
    const float* Wp2 = (const float*)d_in[9];
    const float* rw  = (const float*)d_in[10];

    u16* ws  = (u16*)d_ws;
    u16* ic  = ws;                      // 75.5 MB
    u16* Kl  = ws + IC_ELEMS;
    u16* Ql  = Kl  + TSLOT;
    u16* Vtl = Ql  + TSLOT;
    u16* Kg  = Vtl + TSLOT;
    u16* Qg  = Kg  + TSLOT;
    u16* Vtg = Qg  + TSLOT;
    u16* Otg = Vtg + TSLOT;
    u16* Otl = Otg + TSLOT;

    float* out0 = (float*)d_out;
    float* out1 = out0 + (size_t)TSLOT;

    im2col_prep<<<dim3(128, 16), 256, 0, stream>>>(x_l, x_g, ic);

    conv_gemm<<<dim3(64, 12), 256, 0, stream>>>(
        ic, Wk1, Wq1, Wv1, Wk2, Wq2, Wv2, Kl, Ql, Vtl, Kg, Qg, Vtg);

    // z=0: y_g = attend(Qg, Kl, Vl) -> Otg ; z=1: y_l = attend(Ql, Kg, Vg) -> Otl
    attn_mfma<<<dim3(8, 32, 2), 256, 0, stream>>>(
        Qg, Kl, Vtl, Otg, Ql, Kg, Vtg, Otl);

    // which=0: out0 = x_l + rw*Wp1.y_l ; which=1: out1 = x_g + rw*Wp2.y_g
    proj_mfma<<<dim3(4, 8, 8), 256, 0, stream>>>(
        Wp1, Wp2, Otl, Otg, x_l, x_g, rw, out0, out1);
}

// Round 5
// 381.085 us; speedup vs baseline: 7.3361x; 1.8069x over previous
//
#include <hip/hip_runtime.h>
#include <hip/hip_bf16.h>
#include <stdint.h>

typedef unsigned short u16;
typedef unsigned int u32;

#define TSLOT 2097152            // elements per [4][8][512][128] tensor
#define IC_ELEMS 37748736ull     // 8192 x 4608
#define WB_ELEMS 14155776ull     // 6 x 512 x 4608

typedef __attribute__((ext_vector_type(8))) short short8;
typedef __attribute__((ext_vector_type(8))) unsigned short u16x8;
typedef __attribute__((ext_vector_type(4))) float f32x4;

__device__ __forceinline__ float bf2f(u16 u) {
    union { u32 i; float f; } v; v.i = ((u32)u) << 16; return v.f;
}
__device__ __forceinline__ u16 f2bf(float f) {
    union { u32 i; float f; } v; v.f = f;
    u32 u = v.i;
    return (u16)((u + 0x7FFFu + ((u >> 16) & 1u)) >> 16);  // RNE
}
__device__ __forceinline__ u32 pkbf(float a, float b) {
    __hip_bfloat162 h = __float22bfloat162_rn(make_float2(a, b));
    u32 u; __builtin_memcpy(&u, &h, 4); return u;
}

// async global->LDS, 16B per lane; lds dest must be wave-uniform base.
__device__ __forceinline__ void gl_lds16(const u16* g, u16* l) {
    __builtin_amdgcn_global_load_lds(
        (const __attribute__((address_space(1))) void*)(uintptr_t)(const void*)g,
        (__attribute__((address_space(3))) void*)(uintptr_t)(void*)l,
        16, 0, 0);
}

// ---------------------------------------------------------------------------
// Weight fp32 -> bf16 pre-conversion: wbf[6][512][4608]
// ---------------------------------------------------------------------------
__global__ __launch_bounds__(256) void wconv_prep(
    const float* __restrict__ w0, const float* __restrict__ w1,
    const float* __restrict__ w2, const float* __restrict__ w3,
    const float* __restrict__ w4, const float* __restrict__ w5,
    u16* __restrict__ wbf)
{
    const int tsr = blockIdx.y;
    const float* src = tsr == 0 ? w0 : tsr == 1 ? w1 : tsr == 2 ? w2
                     : tsr == 3 ? w3 : tsr == 4 ? w4 : w5;
    const size_t base = (size_t)blockIdx.x * 4096 + threadIdx.x * 16;
    u16* dst = wbf + (size_t)tsr * 2359296 + base;
    const float4* s4 = (const float4*)(src + base);
    float4 f0 = s4[0], f1 = s4[1], f2 = s4[2], f3 = s4[3];
    u32 p[4];
    p[0] = pkbf(f0.x, f0.y); p[1] = pkbf(f0.z, f0.w);
    p[2] = pkbf(f1.x, f1.y); p[3] = pkbf(f1.z, f1.w);
    *(uint4*)dst = *(uint4*)p;
    p[0] = pkbf(f2.x, f2.y); p[1] = pkbf(f2.z, f2.w);
    p[2] = pkbf(f3.x, f3.y); p[3] = pkbf(f3.z, f3.w);
    *(uint4*)(dst + 8) = *(uint4*)p;
}

// ---------------------------------------------------------------------------
// im2col materialization: ic[m][k] bf16, m = img*4096 + n*1024 + y*32 + x,
// k = ci*9 + ky*3 + kx  (matches OIHW weight flattening).
// ---------------------------------------------------------------------------
__global__ __launch_bounds__(256) void im2col_prep(
    const float* __restrict__ xl, const float* __restrict__ xg,
    u16* __restrict__ ic)
{
    __shared__ float xs[32][4][32];   // [ci_local][y0-1..y0+2][x]

    const int t  = threadIdx.x;
    const int mt = blockIdx.x;        // 0..127
    const int ct = blockIdx.y;        // 0..15
    const int m0 = mt * 64;
    const int img  = m0 >> 12;
    const int m_in = m0 & 4095;
    const int n_i  = m_in >> 10;
    const int y0   = (m_in & 1023) >> 5;

    const float* xp = (img ? xg : xl) + ((size_t)n_i * 512 + ct * 32) * 1024;

    for (int v = t; v < 4096; v += 256) {
        int ci = v >> 7;
        int r  = (v >> 5) & 3;
        int xx = v & 31;
        int yy = y0 - 1 + r;
        xs[ci][r][xx] = ((unsigned)yy < 32u) ? xp[ci * 1024 + yy * 32 + xx] : 0.f;
    }
    __syncthreads();

    const int m_local = t >> 2;
    const int q       = t & 3;
    const int y_sel   = m_local >> 5;
    const int x       = m_local & 31;
    u16* orow = ic + (size_t)(m0 + m_local) * 4608 + (size_t)(ct * 32 + q * 8) * 9;

    #pragma unroll
    for (int c = 0; c < 9; ++c) {
        u16x8 st;
        #pragma unroll
        for (int u = 0; u < 8; ++u) {
            const int e   = c * 8 + u;
            const int cil = q * 8 + e / 9;
            const int tap = e % 9;
            const int ky  = tap / 3, kx = tap % 3;
            int xx = x + kx - 1;
            float v = ((unsigned)xx < 32u) ? xs[cil][y_sel + ky][xx] : 0.f;
            st[u] = f2bf(v);
        }
        *(u16x8*)(orow + c * 8) = st;
    }
}

// ---------------------------------------------------------------------------
// Conv GEMM, m97 structure: BK=64, single-buffered 2-barrier K-loop, all
// staging via global_load_lds (16B). LDS tiles unpadded [128][64] u16 with
// source-side XOR swizzle: chunk_log = chunk_phys ^ (row&7), so fragment
// ds_read_b128 is 2-way bank aliased (free) instead of 16-way.
// 128x128 tile, 4 waves x (4x4 of 16x16x32 bf16), 72 K-iters.
// ---------------------------------------------------------------------------
__global__ __launch_bounds__(256) void conv_gemm(
    const u16* __restrict__ ic, const u16* __restrict__ wbf,
    u16* __restrict__ kl, u16* __restrict__ ql, u16* __restrict__ vl,
    u16* __restrict__ kg, u16* __restrict__ qg, u16* __restrict__ vg)
{
    __shared__ u16 A_lds[128 * 64];
    __shared__ u16 B_lds[128 * 64];

    const int t  = threadIdx.x;
    const int mt = blockIdx.x;   // 0..63
    const int nt = blockIdx.y;   // 0..11
    const int img = mt >> 5;
    const int wt  = nt >> 2;
    const int co0 = (nt & 3) * 128;
    const int m0  = mt * 128;

    u16* osel = img == 0 ? (wt == 0 ? kl : wt == 1 ? ql : vl)
                         : (wt == 0 ? kg : wt == 1 ? qg : vg);
    const u16* wsel = wbf + (size_t)(img * 3 + wt) * 2359296;

    const int lane = t & 63;
    const int w4   = t >> 6;

    // staging: lane covers LDS flat bytes w4*1024 + lane*16 (+ i*4096)
    const int s_rb  = w4 * 8 + (lane >> 3);            // row for issue i: + i*32
    const int s_col = ((lane & 7) ^ (lane >> 3)) * 8;  // swizzled source chunk
    const u16* agp[4];
    const u16* bgp[4];
    #pragma unroll
    for (int i = 0; i < 4; ++i) {
        agp[i] = ic   + (size_t)(m0  + s_rb + i * 32) * 4608 + s_col;
        bgp[i] = wsel + (size_t)(co0 + s_rb + i * 32) * 4608 + s_col;
    }
    u16* Adst = A_lds + w4 * 512;   // wave-uniform; +i*2048 per issue
    u16* Bdst = B_lds + w4 * 512;

    // compute roles
    const int wm = (w4 & 1) * 64;
    const int wn = (w4 >> 1) * 64;
    const int fr = lane & 15;
    const int qd = lane >> 4;
    int arow[4], brow[4];
    #pragma unroll
    for (int i = 0; i < 4; ++i) {
        arow[i] = wm + i * 16 + fr;
        brow[i] = wn + i * 16 + fr;
    }

    f32x4 acc[4][4] = {};

    for (int kb = 0; kb < 4608; kb += 64) {
        __syncthreads();                    // prev compute done, LDS reusable
        #pragma unroll
        for (int i = 0; i < 4; ++i) {
            gl_lds16(agp[i] + kb, Adst + i * 2048);
            gl_lds16(bgp[i] + kb, Bdst + i * 2048);
        }
        __syncthreads();                    // drains vmcnt (loads visible)
        #pragma unroll
        for (int ks = 0; ks < 2; ++ks) {
            short8 af[4], bq[4];
            #pragma unroll
            for (int i = 0; i < 4; ++i) {
                int c = (ks * 4 + qd) ^ (arow[i] & 7);
                af[i] = *(const short8*)&A_lds[arow[i] * 64 + c * 8];
            }
            #pragma unroll
            for (int j = 0; j < 4; ++j) {
                int c = (ks * 4 + qd) ^ (brow[j] & 7);
                bq[j] = *(const short8*)&B_lds[brow[j] * 64 + c * 8];
            }
            #pragma unroll
            for (int i = 0; i < 4; ++i)
                #pragma unroll
                for (int j = 0; j < 4; ++j)
                    acc[i][j] = __builtin_amdgcn_mfma_f32_16x16x32_bf16(
                        af[i], bq[j], acc[i][j], 0, 0, 0);
        }
    }

    const int m_in = m0 & 4095;
    const int n_i  = m_in >> 10;
    const int head = (m_in & 1023) >> 7;
    u16* ob = osel + (size_t)(n_i * 8 + head) * 65536;
    if (wt == 2) {
        // V transposed: [dd][co]
        #pragma unroll
        for (int i = 0; i < 4; ++i) {
            int dd0 = wm + i * 16 + qd * 4;
            #pragma unroll
            for (int j = 0; j < 4; ++j) {
                int co = co0 + wn + j * 16 + fr;
                #pragma unroll
                for (int r = 0; r < 4; ++r)
                    ob[(size_t)(dd0 + r) * 512 + co] = f2bf(acc[i][j][r]);
            }
        }
    } else {
        #pragma unroll
        for (int i = 0; i < 4; ++i) {
            int dd0 = wm + i * 16 + qd * 4;
            #pragma unroll
            for (int j = 0; j < 4; ++j) {
                int co = co0 + wn + j * 16 + fr;
                ushort4 st;
                st.x = f2bf(acc[i][j][0]); st.y = f2bf(acc[i][j][1]);
                st.z = f2bf(acc[i][j][2]); st.w = f2bf(acc[i][j][3]);
                *(ushort4*)(ob + (size_t)co * 128 + dd0) = st;
            }
        }
    }
}

// ---------------------------------------------------------------------------
// MFMA flash attention. Q,K: [nh][c=512][d=128]; V pre-transposed [nh][d][c].
// O^T += V^T.P^T so output lands [s][c] for proj. (verified round 4)
// ---------------------------------------------------------------------------
__global__ __launch_bounds__(256) void attn_mfma(
    const u16* __restrict__ Q0, const u16* __restrict__ K0,
    const u16* __restrict__ V0, u16* __restrict__ O0,
    const u16* __restrict__ Q1, const u16* __restrict__ K1,
    const u16* __restrict__ V1, u16* __restrict__ O1)
{
    __shared__ u16 Qs[64][136];
    __shared__ u16 Ks[64][136];
    __shared__ u16 Vs[128][72];
    __shared__ u16 Ps[64][72];

    const int t    = threadIdx.x;
    const int lane = t & 63;
    const int w    = t >> 6;
    const int qt   = blockIdx.x;
    const int nh   = blockIdx.y;
    const int z    = blockIdx.z;

    const u16* Q = (z ? Q1 : Q0) + (size_t)nh * 65536;
    const u16* K = (z ? K1 : K0) + (size_t)nh * 65536;
    const u16* V = (z ? V1 : V0) + (size_t)nh * 65536;
    u16*       O = (z ? O1 : O0) + (size_t)nh * 65536;

    const int q0 = qt * 64;
    for (int v = t; v < 1024; v += 256) {
        int row = v >> 4, c8 = (v & 15) * 8;
        *(u16x8*)&Qs[row][c8] = *(const u16x8*)(Q + (size_t)(q0 + row) * 128 + c8);
    }

    const int fr  = lane & 15;
    const int qd  = lane >> 4;
    const int koq = qd * 8;

    float m_run[4] = {-3e38f, -3e38f, -3e38f, -3e38f};
    float l_run[4] = {0.f, 0.f, 0.f, 0.f};
    f32x4 Ot[8] = {};
    const float scale = 0.08838834764831845f;

    for (int cb = 0; cb < 8; ++cb) {
        __syncthreads();
        const int kb = cb * 64;
        for (int v = t; v < 1024; v += 256) {
            int row = v >> 4, c8 = (v & 15) * 8;
            *(u16x8*)&Ks[row][c8] = *(const u16x8*)(K + (size_t)(kb + row) * 128 + c8);
        }
        for (int v = t; v < 1024; v += 256) {
            int row = v >> 3, c8 = (v & 7) * 8;
            *(u16x8*)&Vs[row][c8] = *(const u16x8*)(V + (size_t)row * 512 + kb + c8);
        }
        __syncthreads();

        f32x4 s[4] = {};
        #pragma unroll
        for (int dstep = 0; dstep < 4; ++dstep) {
            short8 a = *(const short8*)&Qs[w * 16 + fr][dstep * 32 + koq];
            #pragma unroll
            for (int nj = 0; nj < 4; ++nj) {
                short8 b = *(const short8*)&Ks[nj * 16 + fr][dstep * 32 + koq];
                s[nj] = __builtin_amdgcn_mfma_f32_16x16x32_bf16(a, b, s[nj], 0, 0, 0);
            }
        }

        float al[4];
        #pragma unroll
        for (int r = 0; r < 4; ++r) {
            float mc = fmaxf(fmaxf(s[0][r], s[1][r]), fmaxf(s[2][r], s[3][r])) * scale;
            mc = fmaxf(mc, __shfl_xor(mc, 1));
            mc = fmaxf(mc, __shfl_xor(mc, 2));
            mc = fmaxf(mc, __shfl_xor(mc, 4));
            mc = fmaxf(mc, __shfl_xor(mc, 8));
            float mn = fmaxf(m_run[r], mc);
            al[r] = __expf(m_run[r] - mn);
            m_run[r] = mn;
            float rs = 0.f;
            #pragma unroll
            for (int nj = 0; nj < 4; ++nj) {
                float p = __expf(s[nj][r] * scale - mn);
                s[nj][r] = p;
                rs += p;
            }
            rs += __shfl_xor(rs, 1);
            rs += __shfl_xor(rs, 2);
            rs += __shfl_xor(rs, 4);
            rs += __shfl_xor(rs, 8);
            l_run[r] = l_run[r] * al[r] + rs;
        }

        #pragma unroll
        for (int nj = 0; nj < 4; ++nj)
            #pragma unroll
            for (int r = 0; r < 4; ++r)
                Ps[w * 16 + qd * 4 + r][nj * 16 + fr] = f2bf(s[nj][r]);

        {
            int srcl = (fr >> 2) << 4;
            float a0 = __shfl(al[0], srcl), a1 = __shfl(al[1], srcl);
            float a2 = __shfl(al[2], srcl), a3 = __shfl(al[3], srcl);
            int rsel = fr & 3;
            float ac = rsel == 0 ? a0 : rsel == 1 ? a1 : rsel == 2 ? a2 : a3;
            #pragma unroll
            for (int t8 = 0; t8 < 8; ++t8)
                #pragma unroll
                for (int r = 0; r < 4; ++r)
                    Ot[t8][r] *= ac;
        }

        #pragma unroll
        for (int ks = 0; ks < 2; ++ks) {
            short8 b = *(const short8*)&Ps[w * 16 + fr][ks * 32 + koq];
            #pragma unroll
            for (int t8 = 0; t8 < 8; ++t8) {
                short8 a = *(const short8*)&Vs[t8 * 16 + fr][ks * 32 + koq];
                Ot[t8] = __builtin_amdgcn_mfma_f32_16x16x32_bf16(a, b, Ot[t8], 0, 0, 0);
            }
        }
    }

    int srcl = (fr >> 2) << 4;
    float l0 = __shfl(l_run[0], srcl), l1 = __shfl(l_run[1], srcl);
    float l2 = __shfl(l_run[2], srcl), l3 = __shfl(l_run[3], srcl);
    int rsel = fr & 3;
    float lc = rsel == 0 ? l0 : rsel == 1 ? l1 : rsel == 2 ? l2 : l3;
    float linv = 1.0f / lc;
    int c = q0 + w * 16 + fr;
    #pragma unroll
    for (int t8 = 0; t8 < 8; ++t8)
        #pragma unroll
        for (int r = 0; r < 4; ++r) {
            int d = t8 * 16 + qd * 4 + r;
            O[(size_t)d * 512 + c] = f2bf(Ot[t8][r] * linv);
        }
}

// ---------------------------------------------------------------------------
// Projection GEMM + residual (verified round 4).
// ---------------------------------------------------------------------------
__global__ __launch_bounds__(256) void proj_mfma(
    const float* __restrict__ Wp1, const float* __restrict__ Wp2,
    const u16* __restrict__ Otl, const u16* __restrict__ Otg,
    const float* __restrict__ x_l, const float* __restrict__ x_g,
    const float* __restrict__ rwp,
    float* __restrict__ out0, float* __restrict__ out1)
{
    __shared__ u16 A_lds[128][40];
    __shared__ u16 B_lds[128][40];

    const int t  = threadIdx.x;
    const int ct = blockIdx.x;
    const int st = blockIdx.y;
    const int z  = blockIdx.z;
    const int which = z >> 2;
    const int nn    = z & 3;

    const float* Wp = which ? Wp2 : Wp1;
    const u16*   Ot = (which ? Otg : Otl) + (size_t)nn * 524288;
    const float* xr = (which ? x_g : x_l) + (size_t)nn * 524288;
    float*     outp = (which ? out1 : out0) + (size_t)nn * 524288;

    const int co0 = ct * 128, s0 = st * 128;
    const int row = t & 127, half = t >> 7;
    const float* wrow = Wp + (size_t)(co0 + row) * 512 + half * 16;
    const u16*   brow = Ot + (size_t)(s0 + row) * 512 + half * 16;

    const int lane = t & 63;
    const int wv4  = t >> 6;
    const int wm   = (wv4 & 1) * 64;
    const int wn   = (wv4 >> 1) * 64;
    const int fr   = lane & 15;
    const int koq  = (lane >> 4) * 8;

    f32x4 acc[4][4] = {};

    for (int kb = 0; kb < 512; kb += 32) {
        __syncthreads();
        {
            const float4* wp4 = (const float4*)(wrow + kb);
            float4 f0 = wp4[0], f1 = wp4[1], f2 = wp4[2], f3 = wp4[3];
            u32 p[4];
            p[0] = pkbf(f0.x, f0.y); p[1] = pkbf(f0.z, f0.w);
            p[2] = pkbf(f1.x, f1.y); p[3] = pkbf(f1.z, f1.w);
            *(uint4*)&A_lds[row][half * 16] = *(uint4*)p;
            p[0] = pkbf(f2.x, f2.y); p[1] = pkbf(f2.z, f2.w);
            p[2] = pkbf(f3.x, f3.y); p[3] = pkbf(f3.z, f3.w);
            *(uint4*)&A_lds[row][half * 16 + 8] = *(uint4*)p;
        }
        *(u16x8*)&B_lds[row][half * 16]     = *(const u16x8*)(brow + kb);
        *(u16x8*)&B_lds[row][half * 16 + 8] = *(const u16x8*)(brow + kb + 8);
        __syncthreads();
        short8 af[4], bf[4];
        #pragma unroll
        for (int i = 0; i < 4; ++i) af[i] = *(const short8*)&A_lds[wm + i * 16 + fr][koq];
        #pragma unroll
        for (int j = 0; j < 4; ++j) bf[j] = *(const short8*)&B_lds[wn + j * 16 + fr][koq];
        #pragma unroll
        for (int i = 0; i < 4; ++i)
            #pragma unroll
            for (int j = 0; j < 4; ++j)
                acc[i][j] = __builtin_amdgcn_mfma_f32_16x16x32_bf16(af[i], bf[j], acc[i][j], 0, 0, 0);
    }

    const float rwv = *rwp;
    #pragma unroll
    for (int i = 0; i < 4; ++i) {
        int co_b = co0 + wm + i * 16 + (lane >> 4) * 4;
        #pragma unroll
        for (int j = 0; j < 4; ++j) {
            int s = s0 + wn + j * 16 + fr;
            #pragma unroll
            for (int r = 0; r < 4; ++r) {
                size_t a = (size_t)(co_b + r) * 1024 + s;
                outp[a] = xr[a] + rwv * acc[i][j][r];
            }
        }
    }
}

// ---------------------------------------------------------------------------
extern "C" void kernel_launch(void* const* d_in, const int* in_sizes, int n_in,
                              void* d_out, int out_size, void* d_ws, size_t ws_size,
                              hipStream_t stream) {
    const float* x_l = (const float*)d_in[0];
    const float* x_g = (const float*)d_in[1];
    const float* Wk1 = (const float*)d_in[2];
    const float* Wq1 = (const float*)d_in[3];
    const float* Wv1 = (const float*)d_in[4];
    const float* Wk2 = (const float*)d_in[5];
    const float* Wq2 = (const float*)d_in[6];
    const float* Wv2 = (const float*)d_in[7];
    const float* Wp1 = (const float*)d_in[8];
    const float* Wp2 = (const float*)d_in[9];
    const float* rw  = (const float*)d_in[10];

    u16* ws  = (u16*)d_ws;
    u16* ic  = ws;                       // 75.5 MB
    u16* wbf = ws + IC_ELEMS;            // 28.3 MB
    u16* Kl  = wbf + WB_ELEMS;
    u16* Ql  = Kl  + TSLOT;
    u16* Vtl = Ql  + TSLOT;
    u16* Kg  = Vtl + TSLOT;
    u16* Qg  = Kg  + TSLOT;
    u16* Vtg = Qg  + TSLOT;
    u16* Otg = Vtg + TSLOT;
    u16* Otl = Otg + TSLOT;

    float* out0 = (float*)d_out;
    float* out1 = out0 + (size_t)TSLOT;

    wconv_prep<<<dim3(576, 6), 256, 0, stream>>>(Wk1, Wq1, Wv1, Wk2, Wq2, Wv2, wbf);
    im2col_prep<<<dim3(128, 16), 256, 0, stream>>>(x_l, x_g, ic);

    conv_gemm<<<dim3(64, 12), 256, 0, stream>>>(
        ic, wbf, Kl, Ql, Vtl, Kg, Qg, Vtg);

    attn_mfma<<<dim3(8, 32, 2), 256, 0, stream>>>(
        Qg, Kl, Vtl, Otg, Ql, Kg, Vtg, Otl);

    proj_mfma<<<dim3(4, 8, 8), 256, 0, stream>>>(
        Wp1, Wp2, Otl, Otg, x_l, x_g, rw, out0, out1);
}

// Round 6
// 348.777 us; speedup vs baseline: 8.0156x; 1.0926x over previous
//
#include <hip/hip_runtime.h>
#include <hip/hip_bf16.h>
#include <stdint.h>

typedef unsigned short u16;
typedef unsigned int u32;

#define TSLOT 2097152            // elements per [4][8][512][128] tensor
#define IC_ELEMS 37748736ull     // 8192 x 4608
#define WB_ELEMS 14155776ull     // 6 x 512 x 4608
#define WPB_ELEMS 524288ull      // 2 x 512 x 512

typedef __attribute__((ext_vector_type(8))) short short8;
typedef __attribute__((ext_vector_type(8))) unsigned short u16x8;
typedef __attribute__((ext_vector_type(4))) float f32x4;

__device__ __forceinline__ float bf2f(u16 u) {
    union { u32 i; float f; } v; v.i = ((u32)u) << 16; return v.f;
}
__device__ __forceinline__ u16 f2bf(float f) {
    union { u32 i; float f; } v; v.f = f;
    u32 u = v.i;
    return (u16)((u + 0x7FFFu + ((u >> 16) & 1u)) >> 16);  // RNE
}
__device__ __forceinline__ u32 pkbf(float a, float b) {
    __hip_bfloat162 h = __float22bfloat162_rn(make_float2(a, b));
    u32 u; __builtin_memcpy(&u, &h, 4); return u;
}

// async global->LDS, 16B per lane; lds dest is wave-uniform base + lane*16.
__device__ __forceinline__ void gl_lds16(const u16* g, u16* l) {
    __builtin_amdgcn_global_load_lds(
        (const __attribute__((address_space(1))) void*)(uintptr_t)(const void*)g,
        (__attribute__((address_space(3))) void*)(uintptr_t)(void*)l,
        16, 0, 0);
}

// ---------------------------------------------------------------------------
// prep_all: one launch, three roles.
//  blocks [0,3456):    conv weights fp32->bf16  wbf[6][512][4608]
//  blocks [3456,5504): im2col  ic[8192][4608] bf16
//  blocks [5504,5632): proj weights fp32->bf16  wpb[2][512][512]
// ---------------------------------------------------------------------------
__global__ __launch_bounds__(256) void prep_all(
    const float* __restrict__ xl, const float* __restrict__ xg,
    const float* __restrict__ w0, const float* __restrict__ w1,
    const float* __restrict__ w2, const float* __restrict__ w3,
    const float* __restrict__ w4, const float* __restrict__ w5,
    const float* __restrict__ wp1, const float* __restrict__ wp2,
    u16* __restrict__ wbf, u16* __restrict__ ic, u16* __restrict__ wpb)
{
    __shared__ float xs[32][4][32];
    const int b = blockIdx.x;
    const int t = threadIdx.x;

    if (b < 3456) {
        const int tsr = b / 576, inner = b - tsr * 576;
        const float* src = tsr == 0 ? w0 : tsr == 1 ? w1 : tsr == 2 ? w2
                         : tsr == 3 ? w3 : tsr == 4 ? w4 : w5;
        const size_t base = (size_t)inner * 4096 + t * 16;
        u16* dst = wbf + (size_t)tsr * 2359296 + base;
        const float4* s4 = (const float4*)(src + base);
        float4 f0 = s4[0], f1 = s4[1], f2 = s4[2], f3 = s4[3];
        u32 p[4];
        p[0] = pkbf(f0.x, f0.y); p[1] = pkbf(f0.z, f0.w);
        p[2] = pkbf(f1.x, f1.y); p[3] = pkbf(f1.z, f1.w);
        *(uint4*)dst = *(uint4*)p;
        p[0] = pkbf(f2.x, f2.y); p[1] = pkbf(f2.z, f2.w);
        p[2] = pkbf(f3.x, f3.y); p[3] = pkbf(f3.z, f3.w);
        *(uint4*)(dst + 8) = *(uint4*)p;
        return;
    }
    if (b >= 5504) {
        const int b3 = b - 5504;
        const float* src = (b3 < 64) ? wp1 : wp2;
        const size_t base = (size_t)(b3 & 63) * 4096 + t * 16;
        u16* dst = wpb + ((b3 < 64) ? 0 : 262144) + base;
        const float4* s4 = (const float4*)(src + base);
        float4 f0 = s4[0], f1 = s4[1], f2 = s4[2], f3 = s4[3];
        u32 p[4];
        p[0] = pkbf(f0.x, f0.y); p[1] = pkbf(f0.z, f0.w);
        p[2] = pkbf(f1.x, f1.y); p[3] = pkbf(f1.z, f1.w);
        *(uint4*)dst = *(uint4*)p;
        p[0] = pkbf(f2.x, f2.y); p[1] = pkbf(f2.z, f2.w);
        p[2] = pkbf(f3.x, f3.y); p[3] = pkbf(f3.z, f3.w);
        *(uint4*)(dst + 8) = *(uint4*)p;
        return;
    }

    // im2col
    const int b2 = b - 3456;
    const int mt = b2 >> 4;
    const int ct = b2 & 15;
    const int m0 = mt * 64;
    const int img  = m0 >> 12;
    const int m_in = m0 & 4095;
    const int n_i  = m_in >> 10;
    const int y0   = (m_in & 1023) >> 5;

    const float* xp = (img ? xg : xl) + ((size_t)n_i * 512 + ct * 32) * 1024;

    for (int v = t; v < 4096; v += 256) {
        int ci = v >> 7;
        int r  = (v >> 5) & 3;
        int xx = v & 31;
        int yy = y0 - 1 + r;
        xs[ci][r][xx] = ((unsigned)yy < 32u) ? xp[ci * 1024 + yy * 32 + xx] : 0.f;
    }
    __syncthreads();

    const int m_local = t >> 2;
    const int q       = t & 3;
    const int y_sel   = m_local >> 5;
    const int x       = m_local & 31;
    u16* orow = ic + (size_t)(m0 + m_local) * 4608 + (size_t)(ct * 32 + q * 8) * 9;

    #pragma unroll
    for (int c = 0; c < 9; ++c) {
        u16x8 st;
        #pragma unroll
        for (int u = 0; u < 8; ++u) {
            const int e   = c * 8 + u;
            const int cil = q * 8 + e / 9;
            const int tap = e % 9;
            const int ky  = tap / 3, kx = tap % 3;
            int xx = x + kx - 1;
            float v = ((unsigned)xx < 32u) ? xs[cil][y_sel + ky][xx] : 0.f;
            st[u] = f2bf(v);
        }
        *(u16x8*)(orow + c * 8) = st;
    }
}

// ---------------------------------------------------------------------------
// Conv GEMM (verified round 5): BK=64, 2-barrier K-loop, global_load_lds
// staging, XOR-swizzled unpadded LDS, 128x128 tile, 4 waves, 72 K-iters.
// ---------------------------------------------------------------------------
__global__ __launch_bounds__(256) void conv_gemm(
    const u16* __restrict__ ic, const u16* __restrict__ wbf,
    u16* __restrict__ kl, u16* __restrict__ ql, u16* __restrict__ vl,
    u16* __restrict__ kg, u16* __restrict__ qg, u16* __restrict__ vg)
{
    __shared__ __align__(16) u16 A_lds[128 * 64];
    __shared__ __align__(16) u16 B_lds[128 * 64];

    const int t  = threadIdx.x;
    const int mt = blockIdx.x;
    const int nt = blockIdx.y;
    const int img = mt >> 5;
    const int wt  = nt >> 2;
    const int co0 = (nt & 3) * 128;
    const int m0  = mt * 128;

    u16* osel = img == 0 ? (wt == 0 ? kl : wt == 1 ? ql : vl)
                         : (wt == 0 ? kg : wt == 1 ? qg : vg);
    const u16* wsel = wbf + (size_t)(img * 3 + wt) * 2359296;

    const int lane = t & 63;
    const int w4   = t >> 6;

    const int s_rb  = w4 * 8 + (lane >> 3);
    const int s_col = ((lane & 7) ^ (lane >> 3)) * 8;
    const u16* agp[4];
    const u16* bgp[4];
    #pragma unroll
    for (int i = 0; i < 4; ++i) {
        agp[i] = ic   + (size_t)(m0  + s_rb + i * 32) * 4608 + s_col;
        bgp[i] = wsel + (size_t)(co0 + s_rb + i * 32) * 4608 + s_col;
    }
    u16* Adst = A_lds + w4 * 512;
    u16* Bdst = B_lds + w4 * 512;

    const int wm = (w4 & 1) * 64;
    const int wn = (w4 >> 1) * 64;
    const int fr = lane & 15;
    const int qd = lane >> 4;
    int arow[4], brow[4];
    #pragma unroll
    for (int i = 0; i < 4; ++i) {
        arow[i] = wm + i * 16 + fr;
        brow[i] = wn + i * 16 + fr;
    }

    f32x4 acc[4][4] = {};

    for (int kb = 0; kb < 4608; kb += 64) {
        __syncthreads();
        #pragma unroll
        for (int i = 0; i < 4; ++i) {
            gl_lds16(agp[i] + kb, Adst + i * 2048);
            gl_lds16(bgp[i] + kb, Bdst + i * 2048);
        }
        __syncthreads();
        #pragma unroll
        for (int ks = 0; ks < 2; ++ks) {
            short8 af[4], bq[4];
            #pragma unroll
            for (int i = 0; i < 4; ++i) {
                int c = (ks * 4 + qd) ^ (arow[i] & 7);
                af[i] = *(const short8*)&A_lds[arow[i] * 64 + c * 8];
            }
            #pragma unroll
            for (int j = 0; j < 4; ++j) {
                int c = (ks * 4 + qd) ^ (brow[j] & 7);
                bq[j] = *(const short8*)&B_lds[brow[j] * 64 + c * 8];
            }
            #pragma unroll
            for (int i = 0; i < 4; ++i)
                #pragma unroll
                for (int j = 0; j < 4; ++j)
                    acc[i][j] = __builtin_amdgcn_mfma_f32_16x16x32_bf16(
                        af[i], bq[j], acc[i][j], 0, 0, 0);
        }
    }

    const int m_in = m0 & 4095;
    const int n_i  = m_in >> 10;
    const int head = (m_in & 1023) >> 7;
    u16* ob = osel + (size_t)(n_i * 8 + head) * 65536;
    if (wt == 2) {
        #pragma unroll
        for (int i = 0; i < 4; ++i) {
            int dd0 = wm + i * 16 + qd * 4;
            #pragma unroll
            for (int j = 0; j < 4; ++j) {
                int co = co0 + wn + j * 16 + fr;
                #pragma unroll
                for (int r = 0; r < 4; ++r)
                    ob[(size_t)(dd0 + r) * 512 + co] = f2bf(acc[i][j][r]);
            }
        }
    } else {
        #pragma unroll
        for (int i = 0; i < 4; ++i) {
            int dd0 = wm + i * 16 + qd * 4;
            #pragma unroll
            for (int j = 0; j < 4; ++j) {
                int co = co0 + wn + j * 16 + fr;
                ushort4 st;
                st.x = f2bf(acc[i][j][0]); st.y = f2bf(acc[i][j][1]);
                st.z = f2bf(acc[i][j][2]); st.w = f2bf(acc[i][j][3]);
                *(ushort4*)(ob + (size_t)co * 128 + dd0) = st;
            }
        }
    }
}

// ---------------------------------------------------------------------------
// MFMA flash attention v2: DMA staging for Q/K/V with conv-verified swizzle.
// Q,K split into two [64][64] half-tiles (d 0..63 / 64..127); V [128][64].
// Softmax / P / rescale / epilogue identical to verified round-4 version.
// ---------------------------------------------------------------------------
__global__ __launch_bounds__(256) void attn_mfma(
    const u16* __restrict__ Q0, const u16* __restrict__ K0,
    const u16* __restrict__ V0, u16* __restrict__ O0,
    const u16* __restrict__ Q1, const u16* __restrict__ K1,
    const u16* __restrict__ V1, u16* __restrict__ O1)
{
    __shared__ __align__(16) u16 Qlo[64 * 64];
    __shared__ __align__(16) u16 Qhi[64 * 64];
    __shared__ __align__(16) u16 Klo[64 * 64];
    __shared__ __align__(16) u16 Khi[64 * 64];
    __shared__ __align__(16) u16 Vs[128 * 64];
    __shared__ u16 Ps[64][72];

    const int t    = threadIdx.x;
    const int lane = t & 63;
    const int w    = t >> 6;
    const int qt   = blockIdx.x;
    const int nh   = blockIdx.y;
    const int z    = blockIdx.z;

    const u16* Q = (z ? Q1 : Q0) + (size_t)nh * 65536;
    const u16* K = (z ? K1 : K0) + (size_t)nh * 65536;
    const u16* V = (z ? V1 : V0) + (size_t)nh * 65536;
    u16*       O = (z ? O1 : O0) + (size_t)nh * 65536;

    const int q0    = qt * 64;
    const int s_rb  = w * 8 + (lane >> 3);             // +i*32 per issue
    const int s_col = ((lane & 7) ^ (lane >> 3)) * 8;  // swizzled src chunk
    u16* const dQl = Qlo + w * 512;
    u16* const dQh = Qhi + w * 512;
    u16* const dKl = Klo + w * 512;
    u16* const dKh = Khi + w * 512;
    u16* const dV  = Vs  + w * 512;

    // stage Q (once): rows q0..q0+63, halves d<64 / d>=64
    #pragma unroll
    for (int i = 0; i < 2; ++i) {
        const u16* qr = Q + (size_t)(q0 + s_rb + i * 32) * 128;
        gl_lds16(qr + s_col,      dQl + i * 2048);
        gl_lds16(qr + 64 + s_col, dQh + i * 2048);
    }

    const int fr  = lane & 15;
    const int qd  = lane >> 4;
    const int koq = qd * 8;

    float m_run[4] = {-3e38f, -3e38f, -3e38f, -3e38f};
    float l_run[4] = {0.f, 0.f, 0.f, 0.f};
    f32x4 Ot[8] = {};
    const float scale = 0.08838834764831845f;

    for (int cb = 0; cb < 8; ++cb) {
        __syncthreads();   // prev chunk's LDS reads done
        const int kb = cb * 64;
        #pragma unroll
        for (int i = 0; i < 2; ++i) {
            const u16* kr = K + (size_t)(kb + s_rb + i * 32) * 128;
            gl_lds16(kr + s_col,      dKl + i * 2048);
            gl_lds16(kr + 64 + s_col, dKh + i * 2048);
        }
        #pragma unroll
        for (int i = 0; i < 4; ++i)
            gl_lds16(V + (size_t)(s_rb + i * 32) * 512 + kb + s_col, dV + i * 2048);
        __syncthreads();   // drain DMA

        // S = Q.K^T : 16 q-rows x 64 k-cols per wave
        f32x4 s[4] = {};
        #pragma unroll
        for (int dstep = 0; dstep < 4; ++dstep) {
            const u16* Qh = (dstep < 2) ? Qlo : Qhi;
            const u16* Kh = (dstep < 2) ? Klo : Khi;
            const int cq = (((dstep & 1) * 4 + qd) ^ (fr & 7)) * 8;
            short8 a = *(const short8*)&Qh[(w * 16 + fr) * 64 + cq];
            #pragma unroll
            for (int nj = 0; nj < 4; ++nj) {
                short8 b = *(const short8*)&Kh[(nj * 16 + fr) * 64 + cq];
                s[nj] = __builtin_amdgcn_mfma_f32_16x16x32_bf16(a, b, s[nj], 0, 0, 0);
            }
        }

        // online softmax, row-layout
        float al[4];
        #pragma unroll
        for (int r = 0; r < 4; ++r) {
            float mc = fmaxf(fmaxf(s[0][r], s[1][r]), fmaxf(s[2][r], s[3][r])) * scale;
            mc = fmaxf(mc, __shfl_xor(mc, 1));
            mc = fmaxf(mc, __shfl_xor(mc, 2));
            mc = fmaxf(mc, __shfl_xor(mc, 4));
            mc = fmaxf(mc, __shfl_xor(mc, 8));
            float mn = fmaxf(m_run[r], mc);
            al[r] = __expf(m_run[r] - mn);
            m_run[r] = mn;
            float rs = 0.f;
            #pragma unroll
            for (int nj = 0; nj < 4; ++nj) {
                float p = __expf(s[nj][r] * scale - mn);
                s[nj][r] = p;
                rs += p;
            }
            rs += __shfl_xor(rs, 1);
            rs += __shfl_xor(rs, 2);
            rs += __shfl_xor(rs, 4);
            rs += __shfl_xor(rs, 8);
            l_run[r] = l_run[r] * al[r] + rs;
        }

        // P -> LDS (wave-private rows)
        #pragma unroll
        for (int nj = 0; nj < 4; ++nj)
            #pragma unroll
            for (int r = 0; r < 4; ++r)
                Ps[w * 16 + qd * 4 + r][nj * 16 + fr] = f2bf(s[nj][r]);

        // alpha to column layout
        {
            int srcl = (fr >> 2) << 4;
            float a0 = __shfl(al[0], srcl), a1 = __shfl(al[1], srcl);
            float a2 = __shfl(al[2], srcl), a3 = __shfl(al[3], srcl);
            int rsel = fr & 3;
            float ac = rsel == 0 ? a0 : rsel == 1 ? a1 : rsel == 2 ? a2 : a3;
            #pragma unroll
            for (int t8 = 0; t8 < 8; ++t8)
                #pragma unroll
                for (int r = 0; r < 4; ++r)
                    Ot[t8][r] *= ac;
        }

        // PV: O^T[128 d][16 q] += V^T . P^T
        #pragma unroll
        for (int ks = 0; ks < 2; ++ks) {
            short8 b = *(const short8*)&Ps[w * 16 + fr][ks * 32 + koq];
            #pragma unroll
            for (int t8 = 0; t8 < 8; ++t8) {
                const int cv = ((ks * 4 + qd) ^ (fr & 7)) * 8;
                short8 a = *(const short8*)&Vs[(t8 * 16 + fr) * 64 + cv];
                Ot[t8] = __builtin_amdgcn_mfma_f32_16x16x32_bf16(a, b, Ot[t8], 0, 0, 0);
            }
        }
    }

    int srcl = (fr >> 2) << 4;
    float l0 = __shfl(l_run[0], srcl), l1 = __shfl(l_run[1], srcl);
    float l2 = __shfl(l_run[2], srcl), l3 = __shfl(l_run[3], srcl);
    int rsel = fr & 3;
    float lc = rsel == 0 ? l0 : rsel == 1 ? l1 : rsel == 2 ? l2 : l3;
    float linv = 1.0f / lc;
    int c = q0 + w * 16 + fr;
    #pragma unroll
    for (int t8 = 0; t8 < 8; ++t8)
        #pragma unroll
        for (int r = 0; r < 4; ++r) {
            int d = t8 * 16 + qd * 4 + r;
            O[(size_t)d * 512 + c] = f2bf(Ot[t8][r] * linv);
        }
}

// ---------------------------------------------------------------------------
// Projection GEMM + residual v2: DMA staging (bf16 Wp), BK=64, conv structure.
// out[n][co][s] = x + rw * sum_ci Wp[co][ci] Ot[s][ci]
// ---------------------------------------------------------------------------
__global__ __launch_bounds__(256) void proj_mfma(
    const u16* __restrict__ wpb,
    const u16* __restrict__ Otl, const u16* __restrict__ Otg,
    const float* __restrict__ x_l, const float* __restrict__ x_g,
    const float* __restrict__ rwp,
    float* __restrict__ out0, float* __restrict__ out1)
{
    __shared__ __align__(16) u16 A_lds[128 * 64];
    __shared__ __align__(16) u16 B_lds[128 * 64];

    const int t  = threadIdx.x;
    const int ct = blockIdx.x;        // co tile 0..3
    const int st = blockIdx.y;        // s tile 0..7
    const int z  = blockIdx.z;
    const int which = z >> 2;
    const int nn    = z & 3;

    const u16*   Wp = wpb + (which ? 262144 : 0);
    const u16*   Ot = (which ? Otg : Otl) + (size_t)nn * 524288;
    const float* xr = (which ? x_g : x_l) + (size_t)nn * 524288;
    float*     outp = (which ? out1 : out0) + (size_t)nn * 524288;

    const int co0 = ct * 128, s0 = st * 128;
    const int lane = t & 63;
    const int w4   = t >> 6;

    const int s_rb  = w4 * 8 + (lane >> 3);
    const int s_col = ((lane & 7) ^ (lane >> 3)) * 8;
    const u16* agp[4];
    const u16* bgp[4];
    #pragma unroll
    for (int i = 0; i < 4; ++i) {
        agp[i] = Wp + (size_t)(co0 + s_rb + i * 32) * 512 + s_col;
        bgp[i] = Ot + (size_t)(s0  + s_rb + i * 32) * 512 + s_col;
    }
    u16* Adst = A_lds + w4 * 512;
    u16* Bdst = B_lds + w4 * 512;

    const int wm = (w4 & 1) * 64;
    const int wn = (w4 >> 1) * 64;
    const int fr = lane & 15;
    const int qd = lane >> 4;
    int arow[4], brow[4];
    #pragma unroll
    for (int i = 0; i < 4; ++i) {
        arow[i] = wm + i * 16 + fr;
        brow[i] = wn + i * 16 + fr;
    }

    f32x4 acc[4][4] = {};

    for (int kb = 0; kb < 512; kb += 64) {
        __syncthreads();
        #pragma unroll
        for (int i = 0; i < 4; ++i) {
            gl_lds16(agp[i] + kb, Adst + i * 2048);
            gl_lds16(bgp[i] + kb, Bdst + i * 2048);
        }
        __syncthreads();
        #pragma unroll
        for (int ks = 0; ks < 2; ++ks) {
            short8 af[4], bq[4];
            #pragma unroll
            for (int i = 0; i < 4; ++i) {
                int c = (ks * 4 + qd) ^ (arow[i] & 7);
                af[i] = *(const short8*)&A_lds[arow[i] * 64 + c * 8];
            }
            #pragma unroll
            for (int j = 0; j < 4; ++j) {
                int c = (ks * 4 + qd) ^ (brow[j] & 7);
                bq[j] = *(const short8*)&B_lds[brow[j] * 64 + c * 8];
            }
            #pragma unroll
            for (int i = 0; i < 4; ++i)
                #pragma unroll
                for (int j = 0; j < 4; ++j)
                    acc[i][j] = __builtin_amdgcn_mfma_f32_16x16x32_bf16(
                        af[i], bq[j], acc[i][j], 0, 0, 0);
        }
    }

    const float rwv = *rwp;
    #pragma unroll
    for (int i = 0; i < 4; ++i) {
        int co_b = co0 + wm + i * 16 + qd * 4;
        #pragma unroll
        for (int j = 0; j < 4; ++j) {
            int s = s0 + wn + j * 16 + fr;
            #pragma unroll
            for (int r = 0; r < 4; ++r) {
                size_t a = (size_t)(co_b + r) * 1024 + s;
                outp[a] = xr[a] + rwv * acc[i][j][r];
            }
        }
    }
}

// ---------------------------------------------------------------------------
extern "C" void kernel_launch(void* const* d_in, const int* in_sizes, int n_in,
                              void* d_out, int out_size, void* d_ws, size_t ws_size,
                              hipStream_t stream) {
    const float* x_l = (const float*)d_in[0];
    const float* x_g = (const float*)d_in[1];
    const float* Wk1 = (const float*)d_in[2];
    const float* Wq1 = (const float*)d_in[3];
    const float* Wv1 = (const float*)d_in[4];
    const float* Wk2 = (const float*)d_in[5];
    const float* Wq2 = (const float*)d_in[6];
    const float* Wv2 = (const float*)d_in[7];
    const float* Wp1 = (const float*)d_in[8];
    const float* Wp2 = (const float*)d_in[9];
    const float* rw  = (const float*)d_in[10];

    u16* ws  = (u16*)d_ws;
    u16* ic  = ws;                       // 75.5 MB
    u16* wbf = ws + IC_ELEMS;            // 28.3 MB
    u16* Kl  = wbf + WB_ELEMS;
    u16* Ql  = Kl  + TSLOT;
    u16* Vtl = Ql  + TSLOT;
    u16* Kg  = Vtl + TSLOT;
    u16* Qg  = Kg  + TSLOT;
    u16* Vtg = Qg  + TSLOT;
    u16* Otg = Vtg + TSLOT;
    u16* Otl = Otg + TSLOT;
    u16* wpb = Otl + TSLOT;              // 1 MB

    float* out0 = (float*)d_out;
    float* out1 = out0 + (size_t)TSLOT;

    prep_all<<<5632, 256, 0, stream>>>(
        x_l, x_g, Wk1, Wq1, Wv1, Wk2, Wq2, Wv2, Wp1, Wp2, wbf, ic, wpb);

    conv_gemm<<<dim3(64, 12), 256, 0, stream>>>(
        ic, wbf, Kl, Ql, Vtl, Kg, Qg, Vtg);

    attn_mfma<<<dim3(8, 32, 2), 256, 0, stream>>>(
        Qg, Kl, Vtl, Otg, Ql, Kg, Vtg, Otl);

    proj_mfma<<<dim3(4, 8, 8), 256, 0, stream>>>(
        wpb, Otl, Otg, x_l, x_g, rw, out0, out1);
}

// Round 7
// 339.683 us; speedup vs baseline: 8.2302x; 1.0268x over previous
//
#include <hip/hip_runtime.h>
#include <hip/hip_bf16.h>
#include <stdint.h>

typedef unsigned short u16;
typedef unsigned int u32;

#define TSLOT 2097152              // elements per [4][8][512][128] tensor
#define XT_ELEMS 4734976ull        // 8 x 34 x 34 x 512
#define WB_ELEMS 14155776ull       // 6 x 512 x 4608 (tap-major k')
#define WPB_ELEMS 524288ull        // 2 x 512 x 512

typedef __attribute__((ext_vector_type(8))) short short8;
typedef __attribute__((ext_vector_type(8))) unsigned short u16x8;
typedef __attribute__((ext_vector_type(4))) float f32x4;

__device__ __forceinline__ u16 f2bf(float f) {
    union { u32 i; float f; } v; v.f = f;
    u32 u = v.i;
    return (u16)((u + 0x7FFFu + ((u >> 16) & 1u)) >> 16);  // RNE
}
__device__ __forceinline__ u32 pkbf(float a, float b) {
    __hip_bfloat162 h = __float22bfloat162_rn(make_float2(a, b));
    u32 u; __builtin_memcpy(&u, &h, 4); return u;
}

// async global->LDS, 16B per lane; lds dest is wave-uniform base + lane*16.
// Source address is PER-LANE ARBITRARY (only needs 16B contiguity per lane).
__device__ __forceinline__ void gl_lds16(const u16* g, u16* l) {
    __builtin_amdgcn_global_load_lds(
        (const __attribute__((address_space(1))) void*)(uintptr_t)(const void*)g,
        (__attribute__((address_space(3))) void*)(uintptr_t)(void*)l,
        16, 0, 0);
}

// ---------------------------------------------------------------------------
// prep_all: one launch, three roles.
//  [0,1088):    xt transpose: xt[nimg 8][yy 34][xx 34][ci 512] bf16, zero-pad
//               borders; xt[nimg][y+1][x+1][ci] = x_{img}[n][ci][y][x]
//  [1088,4160): conv-weight reorder fp32->bf16 tap-major:
//               wbf[wt 6][co 512][k'=tap*512+ci] = w[co][ci][tap]
//  [4160,4288): proj weights fp32->bf16  wpb[2][512][512]
// ---------------------------------------------------------------------------
__global__ __launch_bounds__(256) void prep_all(
    const float* __restrict__ xl, const float* __restrict__ xg,
    const float* __restrict__ w0, const float* __restrict__ w1,
    const float* __restrict__ w2, const float* __restrict__ w3,
    const float* __restrict__ w4, const float* __restrict__ w5,
    const float* __restrict__ wp1, const float* __restrict__ wp2,
    u16* __restrict__ xt, u16* __restrict__ wbf, u16* __restrict__ wpb)
{
    __shared__ u16 sh[4608];
    const int b = blockIdx.x;
    const int t = threadIdx.x;

    if (b < 1088) {
        // ---- xt transpose. block = (nimg 0..7, yy 0..33, cig 0..3) ----
        const int nimg = b / 136;
        const int rem  = b - nimg * 136;
        const int yy   = rem >> 2;
        const int cig  = rem & 3;
        const int img  = nimg >> 2, n = nimg & 3;
        const float* srcx = (img ? xg : xl);
        u16* ob = xt + (((size_t)nimg * 34 + yy) * 34) * 512 + cig * 128;

        u16 (*xls)[132] = (u16(*)[132])sh;   // [xx 32][ci 128]
        const bool interior = (yy >= 1 && yy <= 32);
        if (interior) {
            for (int v = t; v < 4096; v += 256) {
                int ci_l = v >> 5, xx0 = v & 31;
                float vv = srcx[(((size_t)n * 512 + cig * 128 + ci_l) * 32 + (yy - 1)) * 32 + xx0];
                xls[xx0][ci_l] = f2bf(vv);
            }
            __syncthreads();
        }
        for (int v = t; v < 544; v += 256) {   // 34 xx * 16 lanes
            int xx = v >> 4, l16 = v & 15;
            u16x8 st;
            if (interior && xx >= 1 && xx <= 32) {
                #pragma unroll
                for (int j = 0; j < 8; ++j) st[j] = xls[xx - 1][l16 * 8 + j];
            } else {
                #pragma unroll
                for (int j = 0; j < 8; ++j) st[j] = 0;
            }
            *(u16x8*)(ob + (size_t)xx * 512 + l16 * 8) = st;
        }
        return;
    }
    if (b < 4160) {
        // ---- conv weight reorder. block = (wt 0..5, co 0..511) ----
        const int idx = b - 1088;
        const int wt = idx >> 9, co = idx & 511;
        const float* srcw = wt == 0 ? w0 : wt == 1 ? w1 : wt == 2 ? w2
                          : wt == 3 ? w3 : wt == 4 ? w4 : w5;
        const float* wr = srcw + (size_t)co * 4608;
        #pragma unroll
        for (int j = 0; j < 18; ++j)
            sh[t * 18 + j] = f2bf(wr[t * 18 + j]);   // sh[k = ci*9+tap]
        __syncthreads();
        u16* orow = wbf + ((size_t)wt * 512 + co) * 4608;
        for (int v = t; v < 4608; v += 256) {
            int tap = v >> 9, ci = v & 511;
            orow[v] = sh[ci * 9 + tap];              // k' = tap*512+ci
        }
        return;
    }
    // ---- proj weights ----
    const int b3 = b - 4160;
    const float* src = (b3 < 64) ? wp1 : wp2;
    const size_t base = (size_t)(b3 & 63) * 4096 + t * 16;
    u16* dst = wpb + ((b3 < 64) ? 0 : 262144) + base;
    const float4* s4 = (const float4*)(src + base);
    float4 f0 = s4[0], f1 = s4[1], f2 = s4[2], f3 = s4[3];
    u32 p[4];
    p[0] = pkbf(f0.x, f0.y); p[1] = pkbf(f0.z, f0.w);
    p[2] = pkbf(f1.x, f1.y); p[3] = pkbf(f1.z, f1.w);
    *(uint4*)dst = *(uint4*)p;
    p[0] = pkbf(f2.x, f2.y); p[1] = pkbf(f2.z, f2.w);
    p[2] = pkbf(f3.x, f3.y); p[3] = pkbf(f3.z, f3.w);
    *(uint4*)(dst + 8) = *(uint4*)p;
}

// ---------------------------------------------------------------------------
// Conv GEMM v3: implicit im2col via per-lane DMA source addressing.
// K tap-major: k' = tap*512 + ci; A[m][k'] = xt[nimg][y(m)+ky][x(m)+kx][ci]
// (xt is +1-padded so ky,kx in 0..2 index directly). BK=64, 2-barrier K-loop,
// XOR-swizzled unpadded LDS, 128x128 tile, 4 waves, 72 K-iters.
// ---------------------------------------------------------------------------
__global__ __launch_bounds__(256) void conv_gemm(
    const u16* __restrict__ xt, const u16* __restrict__ wbf,
    u16* __restrict__ kl, u16* __restrict__ ql, u16* __restrict__ vl,
    u16* __restrict__ kg, u16* __restrict__ qg, u16* __restrict__ vg)
{
    __shared__ __align__(16) u16 A_lds[128 * 64];
    __shared__ __align__(16) u16 B_lds[128 * 64];

    const int t  = threadIdx.x;
    const int mt = blockIdx.x;   // 0..63
    const int nt = blockIdx.y;   // 0..11
    const int img = mt >> 5;
    const int wt  = nt >> 2;
    const int co0 = (nt & 3) * 128;
    const int m0  = mt * 128;
    const int nimg = m0 >> 10;           // 0..7 (img*4 + n)
    const int y0   = (m0 & 1023) >> 5;   // multiple of 4

    u16* osel = img == 0 ? (wt == 0 ? kl : wt == 1 ? ql : vl)
                         : (wt == 0 ? kg : wt == 1 ? qg : vg);

    const int lane = t & 63;
    const int w4   = t >> 6;

    const int s_rb  = w4 * 8 + (lane >> 3);            // +i*32 per issue
    const int s_col = ((lane & 7) ^ (lane >> 3)) * 8;  // swizzled src chunk
    const u16* agp[4];
    const u16* bgp[4];
    #pragma unroll
    for (int i = 0; i < 4; ++i) {
        int ri = s_rb + i * 32;                        // m-row 0..127
        int yy = y0 + (ri >> 5);                       // 0..31 (pad adds +1 via tap)
        int xx = ri & 31;
        agp[i] = xt + (((size_t)nimg * 34 + yy) * 34 + xx) * 512 + s_col;
        bgp[i] = wbf + ((size_t)(img * 3 + wt) * 512 + co0 + s_rb + i * 32) * 4608 + s_col;
    }
    u16* Adst = A_lds + w4 * 512;
    u16* Bdst = B_lds + w4 * 512;

    const int wm = (w4 & 1) * 64;
    const int wn = (w4 >> 1) * 64;
    const int fr = lane & 15;
    const int qd = lane >> 4;
    int arow[4], brow[4];
    #pragma unroll
    for (int i = 0; i < 4; ++i) {
        arow[i] = wm + i * 16 + fr;
        brow[i] = wn + i * 16 + fr;
    }

    f32x4 acc[4][4] = {};

    for (int kb = 0; kb < 4608; kb += 64) {
        const int tap = kb >> 9;           // uniform
        const int ci0 = kb & 511;
        const int ky = tap / 3, kx = tap - ky * 3;
        const int toff = (ky * 34 + kx) * 512 + ci0;   // xt is (+1,+1) pre-padded
        __syncthreads();
        #pragma unroll
        for (int i = 0; i < 4; ++i) {
            gl_lds16(agp[i] + toff, Adst + i * 2048);
            gl_lds16(bgp[i] + kb,   Bdst + i * 2048);
        }
        __syncthreads();
        #pragma unroll
        for (int ks = 0; ks < 2; ++ks) {
            short8 af[4], bq[4];
            #pragma unroll
            for (int i = 0; i < 4; ++i) {
                int c = (ks * 4 + qd) ^ (arow[i] & 7);
                af[i] = *(const short8*)&A_lds[arow[i] * 64 + c * 8];
            }
            #pragma unroll
            for (int j = 0; j < 4; ++j) {
                int c = (ks * 4 + qd) ^ (brow[j] & 7);
                bq[j] = *(const short8*)&B_lds[brow[j] * 64 + c * 8];
            }
            #pragma unroll
            for (int i = 0; i < 4; ++i)
                #pragma unroll
                for (int j = 0; j < 4; ++j)
                    acc[i][j] = __builtin_amdgcn_mfma_f32_16x16x32_bf16(
                        af[i], bq[j], acc[i][j], 0, 0, 0);
        }
    }

    const int m_in = m0 & 4095;
    const int n_i  = m_in >> 10;
    const int head = (m_in & 1023) >> 7;
    u16* ob = osel + (size_t)(n_i * 8 + head) * 65536;
    if (wt == 2) {
        // V transposed: [dd][co]
        #pragma unroll
        for (int i = 0; i < 4; ++i) {
            int dd0 = wm + i * 16 + qd * 4;
            #pragma unroll
            for (int j = 0; j < 4; ++j) {
                int co = co0 + wn + j * 16 + fr;
                #pragma unroll
                for (int r = 0; r < 4; ++r)
                    ob[(size_t)(dd0 + r) * 512 + co] = f2bf(acc[i][j][r]);
            }
        }
    } else {
        #pragma unroll
        for (int i = 0; i < 4; ++i) {
            int dd0 = wm + i * 16 + qd * 4;
            #pragma unroll
            for (int j = 0; j < 4; ++j) {
                int co = co0 + wn + j * 16 + fr;
                ushort4 st;
                st.x = f2bf(acc[i][j][0]); st.y = f2bf(acc[i][j][1]);
                st.z = f2bf(acc[i][j][2]); st.w = f2bf(acc[i][j][3]);
                *(ushort4*)(ob + (size_t)co * 128 + dd0) = st;
            }
        }
    }
}

// ---------------------------------------------------------------------------
// MFMA flash attention v3: Q fragments held in registers (staged once through
// the K LDS buffers); K/V DMA-staged per chunk. LDS 42 KB -> 3 blocks/CU.
// ---------------------------------------------------------------------------
__global__ __launch_bounds__(256) void attn_mfma(
    const u16* __restrict__ Q0, const u16* __restrict__ K0,
    const u16* __restrict__ V0, u16* __restrict__ O0,
    const u16* __restrict__ Q1, const u16* __restrict__ K1,
    const u16* __restrict__ V1, u16* __restrict__ O1)
{
    __shared__ __align__(16) u16 Klo[64 * 64];
    __shared__ __align__(16) u16 Khi[64 * 64];
    __shared__ __align__(16) u16 Vs[128 * 64];
    __shared__ u16 Ps[64][72];

    const int t    = threadIdx.x;
    const int lane = t & 63;
    const int w    = t >> 6;
    const int qt   = blockIdx.x;
    const int nh   = blockIdx.y;
    const int z    = blockIdx.z;

    const u16* Q = (z ? Q1 : Q0) + (size_t)nh * 65536;
    const u16* K = (z ? K1 : K0) + (size_t)nh * 65536;
    const u16* V = (z ? V1 : V0) + (size_t)nh * 65536;
    u16*       O = (z ? O1 : O0) + (size_t)nh * 65536;

    const int q0    = qt * 64;
    const int s_rb  = w * 8 + (lane >> 3);
    const int s_col = ((lane & 7) ^ (lane >> 3)) * 8;
    u16* const dKl = Klo + w * 512;
    u16* const dKh = Khi + w * 512;
    u16* const dV  = Vs  + w * 512;

    const int fr  = lane & 15;
    const int qd  = lane >> 4;
    const int koq = qd * 8;

    // ---- stage Q once through the K buffers, then pull into registers ----
    #pragma unroll
    for (int i = 0; i < 2; ++i) {
        const u16* qr = Q + (size_t)(q0 + s_rb + i * 32) * 128;
        gl_lds16(qr + s_col,      dKl + i * 2048);
        gl_lds16(qr + 64 + s_col, dKh + i * 2048);
    }
    __syncthreads();
    short8 aq[4];
    #pragma unroll
    for (int dstep = 0; dstep < 4; ++dstep) {
        const u16* Qh = (dstep < 2) ? Klo : Khi;
        const int cq = (((dstep & 1) * 4 + qd) ^ (fr & 7)) * 8;
        aq[dstep] = *(const short8*)&Qh[(w * 16 + fr) * 64 + cq];
    }

    float m_run[4] = {-3e38f, -3e38f, -3e38f, -3e38f};
    float l_run[4] = {0.f, 0.f, 0.f, 0.f};
    f32x4 Ot[8] = {};
    const float scale = 0.08838834764831845f;

    for (int cb = 0; cb < 8; ++cb) {
        __syncthreads();   // prev chunk's LDS reads (and Q-frag reads) done
        const int kb = cb * 64;
        #pragma unroll
        for (int i = 0; i < 2; ++i) {
            const u16* kr = K + (size_t)(kb + s_rb + i * 32) * 128;
            gl_lds16(kr + s_col,      dKl + i * 2048);
            gl_lds16(kr + 64 + s_col, dKh + i * 2048);
        }
        #pragma unroll
        for (int i = 0; i < 4; ++i)
            gl_lds16(V + (size_t)(s_rb + i * 32) * 512 + kb + s_col, dV + i * 2048);
        __syncthreads();   // drain DMA

        // S = Q.K^T : 16 q-rows x 64 k-cols per wave
        f32x4 s[4] = {};
        #pragma unroll
        for (int dstep = 0; dstep < 4; ++dstep) {
            const u16* Kh = (dstep < 2) ? Klo : Khi;
            const int cq = (((dstep & 1) * 4 + qd) ^ (fr & 7)) * 8;
            #pragma unroll
            for (int nj = 0; nj < 4; ++nj) {
                short8 bkf = *(const short8*)&Kh[(nj * 16 + fr) * 64 + cq];
                s[nj] = __builtin_amdgcn_mfma_f32_16x16x32_bf16(aq[dstep], bkf, s[nj], 0, 0, 0);
            }
        }

        // online softmax, row-layout
        float al[4];
        #pragma unroll
        for (int r = 0; r < 4; ++r) {
            float mc = fmaxf(fmaxf(s[0][r], s[1][r]), fmaxf(s[2][r], s[3][r])) * scale;
            mc = fmaxf(mc, __shfl_xor(mc, 1));
            mc = fmaxf(mc, __shfl_xor(mc, 2));
            mc = fmaxf(mc, __shfl_xor(mc, 4));
            mc = fmaxf(mc, __shfl_xor(mc, 8));
            float mn = fmaxf(m_run[r], mc);
            al[r] = __expf(m_run[r] - mn);
            m_run[r] = mn;
            float rs = 0.f;
            #pragma unroll
            for (int nj = 0; nj < 4; ++nj) {
                float p = __expf(s[nj][r] * scale - mn);
                s[nj][r] = p;
                rs += p;
            }
            rs += __shfl_xor(rs, 1);
            rs += __shfl_xor(rs, 2);
            rs += __shfl_xor(rs, 4);
            rs += __shfl_xor(rs, 8);
            l_run[r] = l_run[r] * al[r] + rs;
        }

        // P -> LDS (wave-private rows)
        #pragma unroll
        for (int nj = 0; nj < 4; ++nj)
            #pragma unroll
            for (int r = 0; r < 4; ++r)
                Ps[w * 16 + qd * 4 + r][nj * 16 + fr] = f2bf(s[nj][r]);

        // alpha to column layout
        {
            int srcl = (fr >> 2) << 4;
            float a0 = __shfl(al[0], srcl), a1 = __shfl(al[1], srcl);
            float a2 = __shfl(al[2], srcl), a3 = __shfl(al[3], srcl);
            int rsel = fr & 3;
            float ac = rsel == 0 ? a0 : rsel == 1 ? a1 : rsel == 2 ? a2 : a3;
            #pragma unroll
            for (int t8 = 0; t8 < 8; ++t8)
                #pragma unroll
                for (int r = 0; r < 4; ++r)
                    Ot[t8][r] *= ac;
        }

        // PV: O^T[128 d][16 q] += V^T . P^T
        #pragma unroll
        for (int ks = 0; ks < 2; ++ks) {
            short8 b = *(const short8*)&Ps[w * 16 + fr][ks * 32 + koq];
            #pragma unroll
            for (int t8 = 0; t8 < 8; ++t8) {
                const int cv = ((ks * 4 + qd) ^ (fr & 7)) * 8;
                short8 a = *(const short8*)&Vs[(t8 * 16 + fr) * 64 + cv];
                Ot[t8] = __builtin_amdgcn_mfma_f32_16x16x32_bf16(a, b, Ot[t8], 0, 0, 0);
            }
        }
    }

    int srcl = (fr >> 2) << 4;
    float l0 = __shfl(l_run[0], srcl), l1 = __shfl(l_run[1], srcl);
    float l2 = __shfl(l_run[2], srcl), l3 = __shfl(l_run[3], srcl);
    int rsel = fr & 3;
    float lc = rsel == 0 ? l0 : rsel == 1 ? l1 : rsel == 2 ? l2 : l3;
    float linv = 1.0f / lc;
    int c = q0 + w * 16 + fr;
    #pragma unroll
    for (int t8 = 0; t8 < 8; ++t8)
        #pragma unroll
        for (int r = 0; r < 4; ++r) {
            int d = t8 * 16 + qd * 4 + r;
            O[(size_t)d * 512 + c] = f2bf(Ot[t8][r] * linv);
        }
}

// ---------------------------------------------------------------------------
// Projection GEMM + residual (verified round 6): DMA staging, BK=64.
// ---------------------------------------------------------------------------
__global__ __launch_bounds__(256) void proj_mfma(
    const u16* __restrict__ wpb,
    const u16* __restrict__ Otl, const u16* __restrict__ Otg,
    const float* __restrict__ x_l, const float* __restrict__ x_g,
    const float* __restrict__ rwp,
    float* __restrict__ out0, float* __restrict__ out1)
{
    __shared__ __align__(16) u16 A_lds[128 * 64];
    __shared__ __align__(16) u16 B_lds[128 * 64];

    const int t  = threadIdx.x;
    const int ct = blockIdx.x;
    const int st = blockIdx.y;
    const int z  = blockIdx.z;
    const int which = z >> 2;
    const int nn    = z & 3;

    const u16*   Wp = wpb + (which ? 262144 : 0);
    const u16*   Ot = (which ? Otg : Otl) + (size_t)nn * 524288;
    const float* xr = (which ? x_g : x_l) + (size_t)nn * 524288;
    float*     outp = (which ? out1 : out0) + (size_t)nn * 524288;

    const int co0 = ct * 128, s0 = st * 128;
    const int lane = t & 63;
    const int w4   = t >> 6;

    const int s_rb  = w4 * 8 + (lane >> 3);
    const int s_col = ((lane & 7) ^ (lane >> 3)) * 8;
    const u16* agp[4];
    const u16* bgp[4];
    #pragma unroll
    for (int i = 0; i < 4; ++i) {
        agp[i] = Wp + (size_t)(co0 + s_rb + i * 32) * 512 + s_col;
        bgp[i] = Ot + (size_t)(s0  + s_rb + i * 32) * 512 + s_col;
    }
    u16* Adst = A_lds + w4 * 512;
    u16* Bdst = B_lds + w4 * 512;

    const int wm = (w4 & 1) * 64;
    const int wn = (w4 >> 1) * 64;
    const int fr = lane & 15;
    const int qd = lane >> 4;
    int arow[4], brow[4];
    #pragma unroll
    for (int i = 0; i < 4; ++i) {
        arow[i] = wm + i * 16 + fr;
        brow[i] = wn + i * 16 + fr;
    }

    f32x4 acc[4][4] = {};

    for (int kb = 0; kb < 512; kb += 64) {
        __syncthreads();
        #pragma unroll
        for (int i = 0; i < 4; ++i) {
            gl_lds16(agp[i] + kb, Adst + i * 2048);
            gl_lds16(bgp[i] + kb, Bdst + i * 2048);
        }
        __syncthreads();
        #pragma unroll
        for (int ks = 0; ks < 2; ++ks) {
            short8 af[4], bq[4];
            #pragma unroll
            for (int i = 0; i < 4; ++i) {
                int c = (ks * 4 + qd) ^ (arow[i] & 7);
                af[i] = *(const short8*)&A_lds[arow[i] * 64 + c * 8];
            }
            #pragma unroll
            for (int j = 0; j < 4; ++j) {
                int c = (ks * 4 + qd) ^ (brow[j] & 7);
                bq[j] = *(const short8*)&B_lds[brow[j] * 64 + c * 8];
            }
            #pragma unroll
            for (int i = 0; i < 4; ++i)
                #pragma unroll
                for (int j = 0; j < 4; ++j)
                    acc[i][j] = __builtin_amdgcn_mfma_f32_16x16x32_bf16(
                        af[i], bq[j], acc[i][j], 0, 0, 0);
        }
    }

    const float rwv = *rwp;
    #pragma unroll
    for (int i = 0; i < 4; ++i) {
        int co_b = co0 + wm + i * 16 + qd * 4;
        #pragma unroll
        for (int j = 0; j < 4; ++j) {
            int s = s0 + wn + j * 16 + fr;
            #pragma unroll
            for (int r = 0; r < 4; ++r) {
                size_t a = (size_t)(co_b + r) * 1024 + s;
                outp[a] = xr[a] + rwv * acc[i][j][r];
            }
        }
    }
}

// ---------------------------------------------------------------------------
extern "C" void kernel_launch(void* const* d_in, const int* in_sizes, int n_in,
                              void* d_out, int out_size, void* d_ws, size_t ws_size,
                              hipStream_t stream) {
    const float* x_l = (const float*)d_in[0];
    const float* x_g = (const float*)d_in[1];
    const float* Wk1 = (const float*)d_in[2];
    const float* Wq1 = (const float*)d_in[3];
    const float* Wv1 = (const float*)d_in[4];
    const float* Wk2 = (const float*)d_in[5];
    const float* Wq2 = (const float*)d_in[6];
    const float* Wv2 = (const float*)d_in[7];
    const float* Wp1 = (const float*)d_in[8];
    const float* Wp2 = (const float*)d_in[9];
    const float* rw  = (const float*)d_in[10];

    u16* ws  = (u16*)d_ws;
    u16* xt  = ws;                       // 9.5 MB
    u16* wbf = ws + XT_ELEMS;            // 28.3 MB
    u16* Kl  = wbf + WB_ELEMS;
    u16* Ql  = Kl  + TSLOT;
    u16* Vtl = Ql  + TSLOT;
    u16* Kg  = Vtl + TSLOT;
    u16* Qg  = Kg  + TSLOT;
    u16* Vtg = Qg  + TSLOT;
    u16* Otg = Vtg + TSLOT;
    u16* Otl = Otg + TSLOT;
    u16* wpb = Otl + TSLOT;              // 1 MB

    float* out0 = (float*)d_out;
    float* out1 = out0 + (size_t)TSLOT;

    prep_all<<<4288, 256, 0, stream>>>(
        x_l, x_g, Wk1, Wq1, Wv1, Wk2, Wq2, Wv2, Wp1, Wp2, xt, wbf, wpb);

    conv_gemm<<<dim3(64, 12), 256, 0, stream>>>(
        xt, wbf, Kl, Ql, Vtl, Kg, Qg, Vtg);

    attn_mfma<<<dim3(8, 32, 2), 256, 0, stream>>>(
        Qg, Kl, Vtl, Otg, Ql, Kg, Vtg, Otl);

    proj_mfma<<<dim3(4, 8, 8), 256, 0, stream>>>(
        wpb, Otl, Otg, x_l, x_g, rw, out0, out1);
}

// Round 8
// 311.279 us; speedup vs baseline: 8.9812x; 1.0913x over previous
//
#include <hip/hip_runtime.h>
#include <hip/hip_bf16.h>
#include <stdint.h>

typedef unsigned short u16;
typedef unsigned int u32;

#define TSLOT 2097152              // elements per [4][8][512][128] tensor
#define XT_ELEMS 4734976ull        // 8 x 34 x 34 x 512
#define WB_ELEMS 14155776ull       // 6 x 512 x 4608 (tap-major k')
#define WPB_ELEMS 524288ull        // 2 x 512 x 512

typedef __attribute__((ext_vector_type(8))) short short8;
typedef __attribute__((ext_vector_type(8))) unsigned short u16x8;
typedef __attribute__((ext_vector_type(4))) float f32x4;

__device__ __forceinline__ u16 f2bf(float f) {
    union { u32 i; float f; } v; v.f = f;
    u32 u = v.i;
    return (u16)((u + 0x7FFFu + ((u >> 16) & 1u)) >> 16);  // RNE
}
__device__ __forceinline__ u32 pkbf(float a, float b) {
    __hip_bfloat162 h = __float22bfloat162_rn(make_float2(a, b));
    u32 u; __builtin_memcpy(&u, &h, 4); return u;
}

// async global->LDS, 16B per lane; lds dest is wave-uniform base + lane*16.
// Source address is PER-LANE ARBITRARY (only needs 16B contiguity per lane).
__device__ __forceinline__ void gl_lds16(const u16* g, u16* l) {
    __builtin_amdgcn_global_load_lds(
        (const __attribute__((address_space(1))) void*)(uintptr_t)(const void*)g,
        (__attribute__((address_space(3))) void*)(uintptr_t)(void*)l,
        16, 0, 0);
}

// ---------------------------------------------------------------------------
// prep_all: one launch, three roles (verified round 7).
//  [0,1088):    xt transpose: xt[nimg 8][yy 34][xx 34][ci 512] bf16, zero-pad
//  [1088,4160): conv-weight reorder fp32->bf16 tap-major: k' = tap*512+ci
//  [4160,4288): proj weights fp32->bf16  wpb[2][512][512]
// ---------------------------------------------------------------------------
__global__ __launch_bounds__(256) void prep_all(
    const float* __restrict__ xl, const float* __restrict__ xg,
    const float* __restrict__ w0, const float* __restrict__ w1,
    const float* __restrict__ w2, const float* __restrict__ w3,
    const float* __restrict__ w4, const float* __restrict__ w5,
    const float* __restrict__ wp1, const float* __restrict__ wp2,
    u16* __restrict__ xt, u16* __restrict__ wbf, u16* __restrict__ wpb)
{
    __shared__ u16 sh[4608];
    const int b = blockIdx.x;
    const int t = threadIdx.x;

    if (b < 1088) {
        const int nimg = b / 136;
        const int rem  = b - nimg * 136;
        const int yy   = rem >> 2;
        const int cig  = rem & 3;
        const int img  = nimg >> 2, n = nimg & 3;
        const float* srcx = (img ? xg : xl);
        u16* ob = xt + (((size_t)nimg * 34 + yy) * 34) * 512 + cig * 128;

        u16 (*xls)[132] = (u16(*)[132])sh;   // [xx 32][ci 128]
        const bool interior = (yy >= 1 && yy <= 32);
        if (interior) {
            for (int v = t; v < 4096; v += 256) {
                int ci_l = v >> 5, xx0 = v & 31;
                float vv = srcx[(((size_t)n * 512 + cig * 128 + ci_l) * 32 + (yy - 1)) * 32 + xx0];
                xls[xx0][ci_l] = f2bf(vv);
            }
            __syncthreads();
        }
        for (int v = t; v < 544; v += 256) {
            int xx = v >> 4, l16 = v & 15;
            u16x8 st;
            if (interior && xx >= 1 && xx <= 32) {
                #pragma unroll
                for (int j = 0; j < 8; ++j) st[j] = xls[xx - 1][l16 * 8 + j];
            } else {
                #pragma unroll
                for (int j = 0; j < 8; ++j) st[j] = 0;
            }
            *(u16x8*)(ob + (size_t)xx * 512 + l16 * 8) = st;
        }
        return;
    }
    if (b < 4160) {
        const int idx = b - 1088;
        const int wt = idx >> 9, co = idx & 511;
        const float* srcw = wt == 0 ? w0 : wt == 1 ? w1 : wt == 2 ? w2
                          : wt == 3 ? w3 : wt == 4 ? w4 : w5;
        const float* wr = srcw + (size_t)co * 4608;
        #pragma unroll
        for (int j = 0; j < 18; ++j)
            sh[t * 18 + j] = f2bf(wr[t * 18 + j]);   // sh[k = ci*9+tap]
        __syncthreads();
        u16* orow = wbf + ((size_t)wt * 512 + co) * 4608;
        for (int v = t; v < 4608; v += 256) {
            int tap = v >> 9, ci = v & 511;
            orow[v] = sh[ci * 9 + tap];              // k' = tap*512+ci
        }
        return;
    }
    const int b3 = b - 4160;
    const float* src = (b3 < 64) ? wp1 : wp2;
    const size_t base = (size_t)(b3 & 63) * 4096 + t * 16;
    u16* dst = wpb + ((b3 < 64) ? 0 : 262144) + base;
    const float4* s4 = (const float4*)(src + base);
    float4 f0 = s4[0], f1 = s4[1], f2 = s4[2], f3 = s4[3];
    u32 p[4];
    p[0] = pkbf(f0.x, f0.y); p[1] = pkbf(f0.z, f0.w);
    p[2] = pkbf(f1.x, f1.y); p[3] = pkbf(f1.z, f1.w);
    *(uint4*)dst = *(uint4*)p;
    p[0] = pkbf(f2.x, f2.y); p[1] = pkbf(f2.z, f2.w);
    p[2] = pkbf(f3.x, f3.y); p[3] = pkbf(f3.z, f3.w);
    *(uint4*)(dst + 8) = *(uint4*)p;
}

// ---------------------------------------------------------------------------
// Conv GEMM v4: implicit im2col via per-lane DMA, AFFINE K-induction.
// Outer loop over tap (9, address re-derivation), inner over ci0 (8 x 64,
// pure pointer+offset -> strength-reduced). Iteration space identical to v3.
// ---------------------------------------------------------------------------
__global__ __launch_bounds__(256) void conv_gemm(
    const u16* __restrict__ xt, const u16* __restrict__ wbf,
    u16* __restrict__ kl, u16* __restrict__ ql, u16* __restrict__ vl,
    u16* __restrict__ kg, u16* __restrict__ qg, u16* __restrict__ vg)
{
    __shared__ __align__(16) u16 A_lds[128 * 64];
    __shared__ __align__(16) u16 B_lds[128 * 64];

    const int t  = threadIdx.x;
    const int mt = blockIdx.x;   // 0..63
    const int nt = blockIdx.y;   // 0..11
    const int img = mt >> 5;
    const int wt  = nt >> 2;
    const int co0 = (nt & 3) * 128;
    const int m0  = mt * 128;
    const int nimg = m0 >> 10;
    const int y0   = (m0 & 1023) >> 5;

    u16* osel = img == 0 ? (wt == 0 ? kl : wt == 1 ? ql : vl)
                         : (wt == 0 ? kg : wt == 1 ? qg : vg);

    const int lane = t & 63;
    const int w4   = t >> 6;

    const int s_rb  = w4 * 8 + (lane >> 3);
    const int s_col = ((lane & 7) ^ (lane >> 3)) * 8;
    const u16* agp[4];
    const u16* bgp[4];
    #pragma unroll
    for (int i = 0; i < 4; ++i) {
        int ri = s_rb + i * 32;
        int yy = y0 + (ri >> 5);
        int xx = ri & 31;
        agp[i] = xt + (((size_t)nimg * 34 + yy) * 34 + xx) * 512 + s_col;
        bgp[i] = wbf + ((size_t)(img * 3 + wt) * 512 + co0 + s_rb + i * 32) * 4608 + s_col;
    }
    u16* Adst = A_lds + w4 * 512;
    u16* Bdst = B_lds + w4 * 512;

    const int wm = (w4 & 1) * 64;
    const int wn = (w4 >> 1) * 64;
    const int fr = lane & 15;
    const int qd = lane >> 4;
    int arow[4], brow[4];
    #pragma unroll
    for (int i = 0; i < 4; ++i) {
        arow[i] = wm + i * 16 + fr;
        brow[i] = wn + i * 16 + fr;
    }

    f32x4 acc[4][4] = {};

    for (int tap = 0; tap < 9; ++tap) {
        const int ky = tap / 3, kx = tap - ky * 3;
        // per-tap pointer re-derivation (9x total, hoisted out of hot loop)
        const u16* ap[4];
        const u16* bp[4];
        #pragma unroll
        for (int i = 0; i < 4; ++i) {
            ap[i] = agp[i] + (ky * 34 + kx) * 512;   // xt is (+1,+1) pre-padded
            bp[i] = bgp[i] + tap * 512;
        }
        for (int ci0 = 0; ci0 < 512; ci0 += 64) {    // affine induction
            __syncthreads();
            #pragma unroll
            for (int i = 0; i < 4; ++i) {
                gl_lds16(ap[i] + ci0, Adst + i * 2048);
                gl_lds16(bp[i] + ci0, Bdst + i * 2048);
            }
            __syncthreads();
            #pragma unroll
            for (int ks = 0; ks < 2; ++ks) {
                short8 af[4], bq[4];
                #pragma unroll
                for (int i = 0; i < 4; ++i) {
                    int c = (ks * 4 + qd) ^ (arow[i] & 7);
                    af[i] = *(const short8*)&A_lds[arow[i] * 64 + c * 8];
                }
                #pragma unroll
                for (int j = 0; j < 4; ++j) {
                    int c = (ks * 4 + qd) ^ (brow[j] & 7);
                    bq[j] = *(const short8*)&B_lds[brow[j] * 64 + c * 8];
                }
                #pragma unroll
                for (int i = 0; i < 4; ++i)
                    #pragma unroll
                    for (int j = 0; j < 4; ++j)
                        acc[i][j] = __builtin_amdgcn_mfma_f32_16x16x32_bf16(
                            af[i], bq[j], acc[i][j], 0, 0, 0);
            }
        }
    }

    const int m_in = m0 & 4095;
    const int n_i  = m_in >> 10;
    const int head = (m_in & 1023) >> 7;
    u16* ob = osel + (size_t)(n_i * 8 + head) * 65536;
    if (wt == 2) {
        // V transposed: [dd][co]
        #pragma unroll
        for (int i = 0; i < 4; ++i) {
            int dd0 = wm + i * 16 + qd * 4;
            #pragma unroll
            for (int j = 0; j < 4; ++j) {
                int co = co0 + wn + j * 16 + fr;
                #pragma unroll
                for (int r = 0; r < 4; ++r)
                    ob[(size_t)(dd0 + r) * 512 + co] = f2bf(acc[i][j][r]);
            }
        }
    } else {
        #pragma unroll
        for (int i = 0; i < 4; ++i) {
            int dd0 = wm + i * 16 + qd * 4;
            #pragma unroll
            for (int j = 0; j < 4; ++j) {
                int co = co0 + wn + j * 16 + fr;
                ushort4 st;
                st.x = f2bf(acc[i][j][0]); st.y = f2bf(acc[i][j][1]);
                st.z = f2bf(acc[i][j][2]); st.w = f2bf(acc[i][j][3]);
                *(ushort4*)(ob + (size_t)co * 128 + dd0) = st;
            }
        }
    }
}

// ---------------------------------------------------------------------------
// MFMA flash attention v3 (verified round 7): Q in registers, K/V DMA-staged.
// ---------------------------------------------------------------------------
__global__ __launch_bounds__(256) void attn_mfma(
    const u16* __restrict__ Q0, const u16* __restrict__ K0,
    const u16* __restrict__ V0, u16* __restrict__ O0,
    const u16* __restrict__ Q1, const u16* __restrict__ K1,
    const u16* __restrict__ V1, u16* __restrict__ O1)
{
    __shared__ __align__(16) u16 Klo[64 * 64];
    __shared__ __align__(16) u16 Khi[64 * 64];
    __shared__ __align__(16) u16 Vs[128 * 64];
    __shared__ u16 Ps[64][72];

    const int t    = threadIdx.x;
    const int lane = t & 63;
    const int w    = t >> 6;
    const int qt   = blockIdx.x;
    const int nh   = blockIdx.y;
    const int z    = blockIdx.z;

    const u16* Q = (z ? Q1 : Q0) + (size_t)nh * 65536;
    const u16* K = (z ? K1 : K0) + (size_t)nh * 65536;
    const u16* V = (z ? V1 : V0) + (size_t)nh * 65536;
    u16*       O = (z ? O1 : O0) + (size_t)nh * 65536;

    const int q0    = qt * 64;
    const int s_rb  = w * 8 + (lane >> 3);
    const int s_col = ((lane & 7) ^ (lane >> 3)) * 8;
    u16* const dKl = Klo + w * 512;
    u16* const dKh = Khi + w * 512;
    u16* const dV  = Vs  + w * 512;

    const int fr  = lane & 15;
    const int qd  = lane >> 4;
    const int koq = qd * 8;

    #pragma unroll
    for (int i = 0; i < 2; ++i) {
        const u16* qr = Q + (size_t)(q0 + s_rb + i * 32) * 128;
        gl_lds16(qr + s_col,      dKl + i * 2048);
        gl_lds16(qr + 64 + s_col, dKh + i * 2048);
    }
    __syncthreads();
    short8 aq[4];
    #pragma unroll
    for (int dstep = 0; dstep < 4; ++dstep) {
        const u16* Qh = (dstep < 2) ? Klo : Khi;
        const int cq = (((dstep & 1) * 4 + qd) ^ (fr & 7)) * 8;
        aq[dstep] = *(const short8*)&Qh[(w * 16 + fr) * 64 + cq];
    }

    float m_run[4] = {-3e38f, -3e38f, -3e38f, -3e38f};
    float l_run[4] = {0.f, 0.f, 0.f, 0.f};
    f32x4 Ot[8] = {};
    const float scale = 0.08838834764831845f;

    for (int cb = 0; cb < 8; ++cb) {
        __syncthreads();
        const int kb = cb * 64;
        #pragma unroll
        for (int i = 0; i < 2; ++i) {
            const u16* kr = K + (size_t)(kb + s_rb + i * 32) * 128;
            gl_lds16(kr + s_col,      dKl + i * 2048);
            gl_lds16(kr + 64 + s_col, dKh + i * 2048);
        }
        #pragma unroll
        for (int i = 0; i < 4; ++i)
            gl_lds16(V + (size_t)(s_rb + i * 32) * 512 + kb + s_col, dV + i * 2048);
        __syncthreads();

        f32x4 s[4] = {};
        #pragma unroll
        for (int dstep = 0; dstep < 4; ++dstep) {
            const u16* Kh = (dstep < 2) ? Klo : Khi;
            const int cq = (((dstep & 1) * 4 + qd) ^ (fr & 7)) * 8;
            #pragma unroll
            for (int nj = 0; nj < 4; ++nj) {
                short8 bkf = *(const short8*)&Kh[(nj * 16 + fr) * 64 + cq];
                s[nj] = __builtin_amdgcn_mfma_f32_16x16x32_bf16(aq[dstep], bkf, s[nj], 0, 0, 0);
            }
        }

        float al[4];
        #pragma unroll
        for (int r = 0; r < 4; ++r) {
            float mc = fmaxf(fmaxf(s[0][r], s[1][r]), fmaxf(s[2][r], s[3][r])) * scale;
            mc = fmaxf(mc, __shfl_xor(mc, 1));
            mc = fmaxf(mc, __shfl_xor(mc, 2));
            mc = fmaxf(mc, __shfl_xor(mc, 4));
            mc = fmaxf(mc, __shfl_xor(mc, 8));
            float mn = fmaxf(m_run[r], mc);
            al[r] = __expf(m_run[r] - mn);
            m_run[r] = mn;
            float rs = 0.f;
            #pragma unroll
            for (int nj = 0; nj < 4; ++nj) {
                float p = __expf(s[nj][r] * scale - mn);
                s[nj][r] = p;
                rs += p;
            }
            rs += __shfl_xor(rs, 1);
            rs += __shfl_xor(rs, 2);
            rs += __shfl_xor(rs, 4);
            rs += __shfl_xor(rs, 8);
            l_run[r] = l_run[r] * al[r] + rs;
        }

        #pragma unroll
        for (int nj = 0; nj < 4; ++nj)
            #pragma unroll
            for (int r = 0; r < 4; ++r)
                Ps[w * 16 + qd * 4 + r][nj * 16 + fr] = f2bf(s[nj][r]);

        {
            int srcl = (fr >> 2) << 4;
            float a0 = __shfl(al[0], srcl), a1 = __shfl(al[1], srcl);
            float a2 = __shfl(al[2], srcl), a3 = __shfl(al[3], srcl);
            int rsel = fr & 3;
            float ac = rsel == 0 ? a0 : rsel == 1 ? a1 : rsel == 2 ? a2 : a3;
            #pragma unroll
            for (int t8 = 0; t8 < 8; ++t8)
                #pragma unroll
                for (int r = 0; r < 4; ++r)
                    Ot[t8][r] *= ac;
        }

        #pragma unroll
        for (int ks = 0; ks < 2; ++ks) {
            short8 b = *(const short8*)&Ps[w * 16 + fr][ks * 32 + koq];
            #pragma unroll
            for (int t8 = 0; t8 < 8; ++t8) {
                const int cv = ((ks * 4 + qd) ^ (fr & 7)) * 8;
                short8 a = *(const short8*)&Vs[(t8 * 16 + fr) * 64 + cv];
                Ot[t8] = __builtin_amdgcn_mfma_f32_16x16x32_bf16(a, b, Ot[t8], 0, 0, 0);
            }
        }
    }

    int srcl = (fr >> 2) << 4;
    float l0 = __shfl(l_run[0], srcl), l1 = __shfl(l_run[1], srcl);
    float l2 = __shfl(l_run[2], srcl), l3 = __shfl(l_run[3], srcl);
    int rsel = fr & 3;
    float lc = rsel == 0 ? l0 : rsel == 1 ? l1 : rsel == 2 ? l2 : l3;
    float linv = 1.0f / lc;
    int c = q0 + w * 16 + fr;
    #pragma unroll
    for (int t8 = 0; t8 < 8; ++t8)
        #pragma unroll
        for (int r = 0; r < 4; ++r) {
            int d = t8 * 16 + qd * 4 + r;
            O[(size_t)d * 512 + c] = f2bf(Ot[t8][r] * linv);
        }
}

// ---------------------------------------------------------------------------
// Projection GEMM + residual (verified round 6): DMA staging, BK=64.
// ---------------------------------------------------------------------------
__global__ __launch_bounds__(256) void proj_mfma(
    const u16* __restrict__ wpb,
    const u16* __restrict__ Otl, const u16* __restrict__ Otg,
    const float* __restrict__ x_l, const float* __restrict__ x_g,
    const float* __restrict__ rwp,
    float* __restrict__ out0, float* __restrict__ out1)
{
    __shared__ __align__(16) u16 A_lds[128 * 64];
    __shared__ __align__(16) u16 B_lds[128 * 64];

    const int t  = threadIdx.x;
    const int ct = blockIdx.x;
    const int st = blockIdx.y;
    const int z  = blockIdx.z;
    const int which = z >> 2;
    const int nn    = z & 3;

    const u16*   Wp = wpb + (which ? 262144 : 0);
    const u16*   Ot = (which ? Otg : Otl) + (size_t)nn * 524288;
    const float* xr = (which ? x_g : x_l) + (size_t)nn * 524288;
    float*     outp = (which ? out1 : out0) + (size_t)nn * 524288;

    const int co0 = ct * 128, s0 = st * 128;
    const int lane = t & 63;
    const int w4   = t >> 6;

    const int s_rb  = w4 * 8 + (lane >> 3);
    const int s_col = ((lane & 7) ^ (lane >> 3)) * 8;
    const u16* agp[4];
    const u16* bgp[4];
    #pragma unroll
    for (int i = 0; i < 4; ++i) {
        agp[i] = Wp + (size_t)(co0 + s_rb + i * 32) * 512 + s_col;
        bgp[i] = Ot + (size_t)(s0  + s_rb + i * 32) * 512 + s_col;
    }
    u16* Adst = A_lds + w4 * 512;
    u16* Bdst = B_lds + w4 * 512;

    const int wm = (w4 & 1) * 64;
    const int wn = (w4 >> 1) * 64;
    const int fr = lane & 15;
    const int qd = lane >> 4;
    int arow[4], brow[4];
    #pragma unroll
    for (int i = 0; i < 4; ++i) {
        arow[i] = wm + i * 16 + fr;
        brow[i] = wn + i * 16 + fr;
    }

    f32x4 acc[4][4] = {};

    for (int kb = 0; kb < 512; kb += 64) {
        __syncthreads();
        #pragma unroll
        for (int i = 0; i < 4; ++i) {
            gl_lds16(agp[i] + kb, Adst + i * 2048);
            gl_lds16(bgp[i] + kb, Bdst + i * 2048);
        }
        __syncthreads();
        #pragma unroll
        for (int ks = 0; ks < 2; ++ks) {
            short8 af[4], bq[4];
            #pragma unroll
            for (int i = 0; i < 4; ++i) {
                int c = (ks * 4 + qd) ^ (arow[i] & 7);
                af[i] = *(const short8*)&A_lds[arow[i] * 64 + c * 8];
            }
            #pragma unroll
            for (int j = 0; j < 4; ++j) {
                int c = (ks * 4 + qd) ^ (brow[j] & 7);
                bq[j] = *(const short8*)&B_lds[brow[j] * 64 + c * 8];
            }
            #pragma unroll
            for (int i = 0; i < 4; ++i)
                #pragma unroll
                for (int j = 0; j < 4; ++j)
                    acc[i][j] = __builtin_amdgcn_mfma_f32_16x16x32_bf16(
                        af[i], bq[j], acc[i][j], 0, 0, 0);
        }
    }

    const float rwv = *rwp;
    #pragma unroll
    for (int i = 0; i < 4; ++i) {
        int co_b = co0 + wm + i * 16 + qd * 4;
        #pragma unroll
        for (int j = 0; j < 4; ++j) {
            int s = s0 + wn + j * 16 + fr;
            #pragma unroll
            for (int r = 0; r < 4; ++r) {
                size_t a = (size_t)(co_b + r) * 1024 + s;
                outp[a] = xr[a] + rwv * acc[i][j][r];
            }
        }
    }
}

// ---------------------------------------------------------------------------
extern "C" void kernel_launch(void* const* d_in, const int* in_sizes, int n_in,
                              void* d_out, int out_size, void* d_ws, size_t ws_size,
                              hipStream_t stream) {
    const float* x_l = (const float*)d_in[0];
    const float* x_g = (const float*)d_in[1];
    const float* Wk1 = (const float*)d_in[2];
    const float* Wq1 = (const float*)d_in[3];
    const float* Wv1 = (const float*)d_in[4];
    const float* Wk2 = (const float*)d_in[5];
    const float* Wq2 = (const float*)d_in[6];
    const float* Wv2 = (const float*)d_in[7];
    const float* Wp1 = (const float*)d_in[8];
    const float* Wp2 = (const float*)d_in[9];
    const float* rw  = (const float*)d_in[10];

    u16* ws  = (u16*)d_ws;
    u16* xt  = ws;                       // 9.5 MB
    u16* wbf = ws + XT_ELEMS;            // 28.3 MB
    u16* Kl  = wbf + WB_ELEMS;
    u16* Ql  = Kl  + TSLOT;
    u16* Vtl = Ql  + TSLOT;
    u16* Kg  = Vtl + TSLOT;
    u16* Qg  = Kg  + TSLOT;
    u16* Vtg = Qg  + TSLOT;
    u16* Otg = Vtg + TSLOT;
    u16* Otl = Otg + TSLOT;
    u16* wpb = Otl + TSLOT;              // 1 MB

    float* out0 = (float*)d_out;
    float* out1 = out0 + (size_t)TSLOT;

    prep_all<<<4288, 256, 0, stream>>>(
        x_l, x_g, Wk1, Wq1, Wv1, Wk2, Wq2, Wv2, Wp1, Wp2, xt, wbf, wpb);

    conv_gemm<<<dim3(64, 12), 256, 0, stream>>>(
        xt, wbf, Kl, Ql, Vtl, Kg, Qg, Vtg);

    attn_mfma<<<dim3(8, 32, 2), 256, 0, stream>>>(
        Qg, Kl, Vtl, Otg, Ql, Kg, Vtg, Otl);

    proj_mfma<<<dim3(4, 8, 8), 256, 0, stream>>>(
        wpb, Otl, Otg, x_l, x_g, rw, out0, out1);
}